// Round 8
// baseline (998.667 us; speedup 1.0000x reference)
//
#include <hip/hip_runtime.h>
#include <math.h>

typedef unsigned short u16;
typedef unsigned int u32;
typedef unsigned long long u64;

constexpr int kB = 16, kL = 512, kS = 1024, kD = 512, kM = 64;

typedef __attribute__((ext_vector_type(8))) short u16x8;
typedef __attribute__((ext_vector_type(8))) _Float16 f16x8;
typedef __attribute__((ext_vector_type(4))) float f32x4;

__device__ __forceinline__ u16 f2h(float f) {
    _Float16 h = (_Float16)f;
    return *(u16*)&h;
}
__device__ __forceinline__ float h2f(u16 u) {
    _Float16 h = *(_Float16*)&u;
    return (float)h;
}

// ---------------------------------------------------------------------------
// fp16 MFMA GEMM, z-batched: C[z][r,n] = op( sum_k A[z][r,k]*W[z][n,k] + .. )
// 128x128 tile, BK=64. flags: 1=relu, 8=fp16 Ch[r][n], 16=f32 Cout[r][n],
// 32=fp16 transposed Ch[b][n][l], b=r>>lrsh, l=r&((1<<lrsh)-1)
// ---------------------------------------------------------------------------
__global__ __launch_bounds__(256, 4) void gemm_fp16(
    const u16* __restrict__ Abase, const u16* __restrict__ Wbase,
    const float* __restrict__ bias, const float* __restrict__ resid,
    float* __restrict__ Cout, u16* __restrict__ Ch,
    int R, int N, int K, int flags,
    u64 zsA, u64 zsW, u64 zsC, u64 zsR, int lrsh)
{
    __shared__ __attribute__((aligned(16))) u16 Abuf[128 * 64];
    __shared__ __attribute__((aligned(16))) u16 Bbuf[128 * 64];
    const int zz = blockIdx.z;
    Abase += (u64)zz * zsA;
    Wbase += (u64)zz * zsW;
    if (Cout) Cout += (u64)zz * zsC;
    if (Ch)   Ch   += (u64)zz * zsC;
    if (resid) resid += (u64)zz * zsR;

    const int tid = threadIdx.x;
    const int lane = tid & 63;
    const int wave = tid >> 6;
    const int wr = wave >> 1, wc = wave & 1;
    const int ln15 = lane & 15, lq = lane >> 4;
    const int r0 = blockIdx.y * 128, n0 = blockIdx.x * 128;

    f32x4 acc[4][4];
#pragma unroll
    for (int m = 0; m < 4; ++m)
#pragma unroll
        for (int n = 0; n < 4; ++n) acc[m][n] = (f32x4){0.f, 0.f, 0.f, 0.f};

    for (int k0 = 0; k0 < K; k0 += 64) {
        u16x8 av[4], bv[4];
#pragma unroll
        for (int it = 0; it < 4; ++it) {
            int c = it * 256 + tid;
            int row = c >> 3, j = c & 7;
            int jj = j ^ (row & 7);
            av[it] = *(const u16x8*)(Abase + (size_t)(r0 + row) * K + k0 + jj * 8);
            bv[it] = *(const u16x8*)(Wbase + (size_t)(n0 + row) * K + k0 + jj * 8);
        }
        __syncthreads();
#pragma unroll
        for (int it = 0; it < 4; ++it) {
            int c = it * 256 + tid;
            int row = c >> 3, j = c & 7;
            *(u16x8*)&Abuf[row * 64 + j * 8] = av[it];
            *(u16x8*)&Bbuf[row * 64 + j * 8] = bv[it];
        }
        __syncthreads();
#pragma unroll
        for (int h = 0; h < 2; ++h) {
            int kg = lq + h * 4;
            f16x8 af[4], bfv[4];
#pragma unroll
            for (int m = 0; m < 4; ++m) {
                int row = wr * 64 + m * 16 + ln15;
                af[m] = *(const f16x8*)&Abuf[row * 64 + ((kg ^ (row & 7)) << 3)];
            }
#pragma unroll
            for (int n = 0; n < 4; ++n) {
                int col = wc * 64 + n * 16 + ln15;
                bfv[n] = *(const f16x8*)&Bbuf[col * 64 + ((kg ^ (col & 7)) << 3)];
            }
#pragma unroll
            for (int m = 0; m < 4; ++m)
#pragma unroll
                for (int n = 0; n < 4; ++n)
                    acc[m][n] = __builtin_amdgcn_mfma_f32_16x16x32_f16(af[m], bfv[n], acc[m][n], 0, 0, 0);
        }
        __syncthreads();
    }

#pragma unroll
    for (int m = 0; m < 4; ++m) {
#pragma unroll
        for (int n = 0; n < 4; ++n) {
            int gc = n0 + wc * 64 + n * 16 + ln15;
            float bv_ = bias ? bias[gc] : 0.f;
            int gr0 = r0 + wr * 64 + m * 16 + lq * 4;
            float v[4];
#pragma unroll
            for (int rg = 0; rg < 4; ++rg) {
                int gr = gr0 + rg;
                float val = acc[m][n][rg] + bv_;
                if (resid) val += resid[(size_t)gr * N + gc];
                if (flags & 1) val = fmaxf(val, 0.f);
                if (flags & 16) Cout[(size_t)gr * N + gc] = val;
                if (flags & 8)  Ch[(size_t)gr * N + gc] = f2h(val);
                v[rg] = val;
            }
            if (flags & 32) {
                int bb = gr0 >> lrsh;
                int l_ = gr0 & ((1 << lrsh) - 1);
                ushort4 o;
                o.x = f2h(v[0]); o.y = f2h(v[1]); o.z = f2h(v[2]); o.w = f2h(v[3]);
                *(ushort4*)&Ch[(((size_t)bb * N + gc) << lrsh) + l_] = o;
            }
        }
    }
}

// ---------------------------------------------------------------------------
// 64x64-tile fp16 GEMM for thin/batched shapes. Same flags as gemm_fp16.
// ---------------------------------------------------------------------------
__global__ __launch_bounds__(256, 4) void gemm64(
    const u16* __restrict__ Abase, const u16* __restrict__ Wbase,
    const float* __restrict__ bias, const float* __restrict__ resid,
    float* __restrict__ Cout, u16* __restrict__ Ch,
    int R, int N, int K, int flags,
    u64 zsA, u64 zsW, u64 zsC, u64 zsR, int lrsh)
{
    __shared__ __attribute__((aligned(16))) u16 Abuf[64 * 64];
    __shared__ __attribute__((aligned(16))) u16 Bbuf[64 * 64];
    const int zz = blockIdx.z;
    Abase += (u64)zz * zsA;
    Wbase += (u64)zz * zsW;
    if (Cout) Cout += (u64)zz * zsC;
    if (Ch)   Ch   += (u64)zz * zsC;
    if (resid) resid += (u64)zz * zsR;

    const int tid = threadIdx.x;
    const int lane = tid & 63;
    const int w = tid >> 6;
    const int ln15 = lane & 15, lq = lane >> 4;
    const int r0 = blockIdx.y * 64, n0 = blockIdx.x * 64;

    f32x4 acc[4];
#pragma unroll
    for (int m = 0; m < 4; ++m) acc[m] = (f32x4){0.f, 0.f, 0.f, 0.f};

    for (int k0 = 0; k0 < K; k0 += 64) {
        u16x8 av[2], bv[2];
#pragma unroll
        for (int it = 0; it < 2; ++it) {
            int c = it * 256 + tid;
            int row = c >> 3, j = c & 7;
            int jj = j ^ (row & 7);
            av[it] = *(const u16x8*)(Abase + (size_t)(r0 + row) * K + k0 + jj * 8);
            bv[it] = *(const u16x8*)(Wbase + (size_t)(n0 + row) * K + k0 + jj * 8);
        }
        __syncthreads();
#pragma unroll
        for (int it = 0; it < 2; ++it) {
            int c = it * 256 + tid;
            int row = c >> 3, j = c & 7;
            *(u16x8*)&Abuf[row * 64 + j * 8] = av[it];
            *(u16x8*)&Bbuf[row * 64 + j * 8] = bv[it];
        }
        __syncthreads();
#pragma unroll
        for (int h = 0; h < 2; ++h) {
            int kg = lq + h * 4;
            int col = w * 16 + ln15;
            f16x8 bf = *(const f16x8*)&Bbuf[col * 64 + ((kg ^ (col & 7)) << 3)];
#pragma unroll
            for (int m = 0; m < 4; ++m) {
                int row = m * 16 + ln15;
                f16x8 af = *(const f16x8*)&Abuf[row * 64 + ((kg ^ (row & 7)) << 3)];
                acc[m] = __builtin_amdgcn_mfma_f32_16x16x32_f16(af, bf, acc[m], 0, 0, 0);
            }
        }
        __syncthreads();
    }

    const int gc = n0 + w * 16 + ln15;
    const float bv_ = bias ? bias[gc] : 0.f;
#pragma unroll
    for (int m = 0; m < 4; ++m) {
        int gr0 = r0 + m * 16 + lq * 4;
        float v[4];
#pragma unroll
        for (int rg = 0; rg < 4; ++rg) {
            int gr = gr0 + rg;
            float val = acc[m][rg] + bv_;
            if (resid) val += resid[(size_t)gr * N + gc];
            if (flags & 1) val = fmaxf(val, 0.f);
            if (flags & 16) Cout[(size_t)gr * N + gc] = val;
            if (flags & 8)  Ch[(size_t)gr * N + gc] = f2h(val);
            v[rg] = val;
        }
        if (flags & 32) {
            int bb = gr0 >> lrsh;
            int l_ = gr0 & ((1 << lrsh) - 1);
            ushort4 o;
            o.x = f2h(v[0]); o.y = f2h(v[1]); o.z = f2h(v[2]); o.w = f2h(v[3]);
            *(ushort4*)&Ch[(((size_t)bb * N + gc) << lrsh) + l_] = o;
        }
    }
}

// ---------------------------------------------------------------------------
// Fused prep: all weight casts, K|V weight/bias concat, cross cast, twiddles.
// ---------------------------------------------------------------------------
__global__ __launch_bounds__(256) void prep(
    const float* __restrict__ wq, const float* __restrict__ wk,
    const float* __restrict__ wv, const float* __restrict__ wo,
    const float* __restrict__ ff1, const float* __restrict__ ff2,
    const float* __restrict__ dw1, const float* __restrict__ dw2,
    const float* __restrict__ dw3, const float* __restrict__ cross,
    const float* __restrict__ bk, const float* __restrict__ bv,
    u16* __restrict__ wqh, u16* __restrict__ wkvh, u16* __restrict__ woh,
    u16* __restrict__ ff1h, u16* __restrict__ ff2h,
    u16* __restrict__ d1w1h, u16* __restrict__ d2w1h, u16* __restrict__ d3w1h,
    u16* __restrict__ crossh, float* __restrict__ bkv,
    u16* __restrict__ tw512, u16* __restrict__ tw1024, u16* __restrict__ tih)
{
    const int gid = blockIdx.x * 256 + threadIdx.x;
    const int stride = gridDim.x * 256;
    for (int i = gid; i < 262144; i += stride) wqh[i] = f2h(wq[i]);
    for (int i = gid; i < 262144; i += stride) wkvh[i] = f2h(wk[i]);
    for (int i = gid; i < 262144; i += stride) wkvh[262144 + i] = f2h(wv[i]);
    for (int i = gid; i < 262144; i += stride) woh[i] = f2h(wo[i]);
    for (int i = gid; i < 1048576; i += stride) ff1h[i] = f2h(ff1[i]);
    for (int i = gid; i < 1048576; i += stride) ff2h[i] = f2h(ff2[i]);
    for (int i = gid; i < 131072; i += stride) d1w1h[i] = f2h(dw1[i]);
    for (int i = gid; i < 131072; i += stride) d2w1h[i] = f2h(dw2[i]);
    for (int i = gid; i < 131072; i += stride) d3w1h[i] = f2h(dw3[i]);
    const float4* c4 = (const float4*)cross;
    for (int i = gid; i < 2097152; i += stride) {
        float4 v = c4[i];
        ushort4 o;
        o.x = f2h(v.x); o.y = f2h(v.y); o.z = f2h(v.z); o.w = f2h(v.w);
        *(ushort4*)&crossh[i * 4] = o;
    }
    for (int i = gid; i < 1024; i += stride) bkv[i] = (i < 512) ? bk[i] : bv[i - 512];
    for (int i = gid; i < 65536; i += stride) {
        int r = i >> 9, l = i & 511;
        int m = r & 63;
        int ph = (m * l) & 511;
        float ang = 6.283185307179586f * (float)ph / 512.0f;
        float s_, c_;
        sincosf(ang, &s_, &c_);
        tw512[i] = f2h((r < 64) ? c_ : -s_);
    }
    for (int i = gid; i < 131072; i += stride) {
        int r = i >> 10, l = i & 1023;
        int m = r & 63;
        int ph = (m * l) & 1023;
        float ang = 6.283185307179586f * (float)ph / 1024.0f;
        float s_, c_;
        sincosf(ang, &s_, &c_);
        tw1024[i] = f2h((r < 64) ? c_ : -s_);
    }
    for (int i = gid; i < 65536; i += stride) {
        int l = i >> 7, r = i & 127;
        int m = r & 63;
        int ph = (m * l) & 511;
        float ang = 6.283185307179586f * (float)ph / 512.0f;
        float s_, c_;
        sincosf(ang, &s_, &c_);
        float val;
        if (r == 0) val = 1.0f / 512.0f;
        else if (r < 64) val = 2.0f * c_ / 512.0f;
        else if (r == 64) val = 0.0f;
        else val = -2.0f * s_ / 512.0f;
        tih[i] = f2h(val);
    }
}

// ---------------------------------------------------------------------------
// Transpose+cast x[b][l][d] fp32 -> xT[b][d][l] fp16. 64x64 LDS tiles.
// ---------------------------------------------------------------------------
__global__ __launch_bounds__(256) void tr_cast_x(
    const float* __restrict__ x, u16* __restrict__ xt)
{
    __shared__ u16 t[64][72];
    const int b = blockIdx.y;
    const int lt = (blockIdx.x >> 3) * 64, dt = (blockIdx.x & 7) * 64;
    const int tid = threadIdx.x;
#pragma unroll
    for (int rep = 0; rep < 16; ++rep) {
        int idx = tid + rep * 256;
        int row = idx >> 6, col = idx & 63;
        t[row][col] = f2h(x[((size_t)b * kL + lt + row) * kD + dt + col]);
    }
    __syncthreads();
#pragma unroll
    for (int rep = 0; rep < 16; ++rep) {
        int idx = tid + rep * 256;
        int row = idx >> 6, col = idx & 63;
        xt[((size_t)b * kD + dt + row) * kL + lt + col] = t[col][row];
    }
}

// ---------------------------------------------------------------------------
// Spectral transpose for FEB: QF[b][128][512] fp32 -> QTr/QTi [d][b][m] fp32.
// ---------------------------------------------------------------------------
__global__ __launch_bounds__(256) void spec_tr(
    const float* __restrict__ QF, float* __restrict__ qtr, float* __restrict__ qti)
{
    __shared__ float t0[64][65], t1[64][65];
    const int b = blockIdx.y;
    const int dt = blockIdx.x * 64;
    const int tid = threadIdx.x;
    const float* QFb = QF + (size_t)b * 128 * 512;
#pragma unroll
    for (int rep = 0; rep < 16; ++rep) {
        int idx = tid + rep * 256;
        int m = idx >> 6, dd = idx & 63;
        t0[m][dd] = QFb[(size_t)m * 512 + dt + dd];
        t1[m][dd] = QFb[(size_t)(64 + m) * 512 + dt + dd];
    }
    __syncthreads();
#pragma unroll
    for (int rep = 0; rep < 16; ++rep) {
        int idx = tid + rep * 256;
        int dd = idx >> 6, m = idx & 63;
        size_t o = ((size_t)(dt + dd) * kB + b) * kM + m;
        qtr[o] = t0[m][dd];
        qti[o] = t1[m][dd];
    }
}

// ---------------------------------------------------------------------------
// FEB contraction v3: v1 thread structure (1 e x 16 b, 32 acc regs -- known
// non-spilling) + wide grid (128 eb x 8 ch = 1024 blocks = 4/CU).
// e = eb*4 + (tid>>6); d-chunk 64 per block. Partials float2 (r,i).
// ---------------------------------------------------------------------------
__global__ __launch_bounds__(256, 2) void feb_part3(
    const float* __restrict__ qtr, const float* __restrict__ qti,
    const float* __restrict__ wr, const float* __restrict__ wi,
    float2* __restrict__ part)
{
    __shared__ float sqr[4][16][64], sqi[4][16][64];
    const int eb = blockIdx.x, ch = blockIdx.y;
    const int tid = threadIdx.x;
    const int mm = tid & 63, ee = tid >> 6;
    const int e = eb * 4 + ee;

    float ar[16], ai[16];
#pragma unroll
    for (int b = 0; b < 16; ++b) { ar[b] = 0.f; ai[b] = 0.f; }

    const int dbeg = ch * 64, dend = dbeg + 64;
    for (int d0 = dbeg; d0 < dend; d0 += 4) {
        __syncthreads();
#pragma unroll
        for (int rep = 0; rep < 16; ++rep) {
            int idx = tid + rep * 256;
            int m_ = idx & 63, b_ = (idx >> 6) & 15, dd_ = idx >> 10;
            size_t g = (size_t)(d0 + dd_) * 1024 + b_ * 64 + m_;
            sqr[dd_][b_][m_] = qtr[g];
            sqi[dd_][b_][m_] = qti[g];
        }
        __syncthreads();
#pragma unroll
        for (int dd = 0; dd < 4; ++dd) {
            size_t wofs = ((size_t)(d0 + dd) * 512 + e) * 64 + mm;
            float wrv = wr[wofs], wiv = wi[wofs];
#pragma unroll
            for (int b = 0; b < 16; ++b) {
                float qr = sqr[dd][b][mm], qi = sqi[dd][b][mm];
                ar[b] += qr * wrv - qi * wiv;
                ai[b] += qr * wiv + qi * wrv;
            }
        }
    }
#pragma unroll
    for (int b = 0; b < 16; ++b)
        part[((size_t)(ch * 512 + e) * 16 + b) * 64 + mm] = make_float2(ar[b], ai[b]);
}

// Reduce 8 chunk-partials -> OMT fp16 [b][e][r] (r<64 real, r>=64 imag)
__global__ __launch_bounds__(256) void feb_reduce(
    const float2* __restrict__ part, u16* __restrict__ OMT)
{
    int idx = blockIdx.x * 256 + threadIdx.x;   // 0..524287
    int m = idx & 63, e = (idx >> 6) & 511, b = idx >> 15;
    float r = 0.f, im = 0.f;
#pragma unroll
    for (int ch = 0; ch < 8; ++ch) {
        float2 v = part[((size_t)(ch * 512 + e) * 16 + b) * 64 + m];
        r += v.x;
        im += v.y;
    }
    u16* o = OMT + ((size_t)(b * 512 + e)) * 128;
    o[m] = f2h(r);
    o[64 + m] = f2h(im);
}

// ---------------------------------------------------------------------------
// Spectral cross attention, one block per (b,h). QF fp32 [b][128][512];
// KVF fp32 [b][128][1024]. Output OMT fp16 [b][e][r].
// ---------------------------------------------------------------------------
__global__ __launch_bounds__(256) void spectral_attn(
    const float* __restrict__ QF, const float* __restrict__ KVF,
    u16* __restrict__ OMT)
{
    __shared__ float kr[64][65], ki[64][65], sat[64][65];
    const int b = blockIdx.x >> 3, h = blockIdx.x & 7;
    const int tid = threadIdx.x;
    const int dbase = h * 64;
    const float* KVFb = KVF + (size_t)b * 128 * 1024;

    for (int idx = tid; idx < 4096; idx += 256) {
        int j = idx >> 6, dd = idx & 63;
        kr[j][dd] = KVFb[(size_t)j * 1024 + dbase + dd];
        ki[j][dd] = KVFb[(size_t)(64 + j) * 1024 + dbase + dd];
    }
    __syncthreads();

    const int i_ = tid >> 2, jg = tid & 3;
    float s[16];
#pragma unroll
    for (int jj = 0; jj < 16; ++jj) s[jj] = 0.f;
    const float* qrp = QF + ((size_t)b * 128 + i_) * 512 + dbase;
    const float* qip = qrp + (size_t)64 * 512;
    for (int dd = 0; dd < 64; ++dd) {
        float qr = qrp[dd], qi = qip[dd];
#pragma unroll
        for (int jj = 0; jj < 16; ++jj) {
            int j = jg * 16 + jj;
            s[jj] += qr * kr[j][dd] + qi * ki[j][dd];
        }
    }
    float mx = s[0];
#pragma unroll
    for (int jj = 1; jj < 16; ++jj) mx = fmaxf(mx, s[jj]);
    mx = fmaxf(mx, __shfl_xor(mx, 1));
    mx = fmaxf(mx, __shfl_xor(mx, 2));
    float sum = 0.f;
#pragma unroll
    for (int jj = 0; jj < 16; ++jj) { s[jj] = expf(s[jj] - mx); sum += s[jj]; }
    sum += __shfl_xor(sum, 1);
    sum += __shfl_xor(sum, 2);
    float rinv = 1.0f / sum;
#pragma unroll
    for (int jj = 0; jj < 16; ++jj) sat[i_][jg * 16 + jj] = s[jj] * rinv;
    __syncthreads();

    const int dd = tid & 63, ig = tid >> 6;
    float ar[16], ai[16];
#pragma unroll
    for (int ii = 0; ii < 16; ++ii) { ar[ii] = 0.f; ai[ii] = 0.f; }
    const float* VFb = KVFb + 512 + dbase + dd;
    for (int j = 0; j < 64; ++j) {
        float vr = VFb[(size_t)j * 1024];
        float vi = VFb[(size_t)(64 + j) * 1024];
#pragma unroll
        for (int ii = 0; ii < 16; ++ii) {
            float a = sat[ig * 16 + ii][j];
            ar[ii] += a * vr;
            ai[ii] += a * vi;
        }
    }
    u16* o = OMT + ((size_t)(b * 512 + dbase + dd)) * 128 + ig * 16;
    u16x8 v0, v1, w0, w1;
#pragma unroll
    for (int q = 0; q < 8; ++q) {
        v0[q] = (short)f2h(ar[q]);     v1[q] = (short)f2h(ar[8 + q]);
        w0[q] = (short)f2h(ai[q]);     w1[q] = (short)f2h(ai[8 + q]);
    }
    *(u16x8*)(o) = v0;
    *(u16x8*)(o + 8) = v1;
    *(u16x8*)(o + 64) = w0;
    *(u16x8*)(o + 72) = w1;
}

// ---------------------------------------------------------------------------
// MoE decomposition epilogue.
// ---------------------------------------------------------------------------
__global__ __launch_bounds__(256) void decomp_apply(
    const float* __restrict__ x, const float* __restrict__ logits,
    float* __restrict__ xout, u16* __restrict__ xout_h, u16* __restrict__ tout_h)
{
    int idx = blockIdx.x * 256 + threadIdx.x;
    if (idx >= kB * kL * kD) return;
    int d = idx & 511;
    int l = (idx >> 9) & 511;
    int b = idx >> 18;
    const float* lg = logits + ((size_t)b * kL + l) * 3;
    float g0 = lg[0], g1 = lg[1], g2 = lg[2];
    float m = fmaxf(g0, fmaxf(g1, g2));
    float e0 = expf(g0 - m), e1 = expf(g1 - m), e2 = expf(g2 - m);
    float inv = 1.0f / (e0 + e1 + e2);
    g0 = e0 * inv; g1 = e1 * inv; g2 = e2 * inv;

    const float* xb = x + (size_t)b * kL * kD + d;
    float v[7];
#pragma unroll
    for (int j = 0; j < 7; ++j) {
        int ls = l + j - 3;
        v[j] = (ls >= 0 && ls < kL) ? xb[(size_t)ls * kD] : 0.f;
    }
    float s3 = (v[2] + v[3] + v[4]) * (1.0f / 3.0f);
    float s5 = (v[1] + v[2] + v[3] + v[4] + v[5]) * 0.2f;
    float s7 = (v[0] + v[1] + v[2] + v[3] + v[4] + v[5] + v[6]) * (1.0f / 7.0f);
    float trend = g0 * s3 + g1 * s5 + g2 * s7;
    float res = v[3] - trend;
    if (xout) xout[idx] = res;
    if (xout_h) xout_h[idx] = f2h(res);
    tout_h[idx] = f2h(trend);
}

// ---------------------------------------------------------------------------
// Gate layer 2, K-quarter split: thread (row, q); shuffle-combine over quad.
// grid 128 x 256.
// ---------------------------------------------------------------------------
__global__ __launch_bounds__(256) void gate2(
    const u16* __restrict__ GH, const float* __restrict__ w2,
    const float* __restrict__ b2, float* __restrict__ logits)
{
    __shared__ float w2l[3][256];
    int tid = threadIdx.x;
    for (int i = tid; i < 768; i += 256) w2l[i >> 8][i & 255] = w2[i];
    __syncthreads();
    int gid = blockIdx.x * 256 + tid;
    int r = gid >> 2, q = gid & 3;
    float s0 = 0.f, s1 = 0.f, s2 = 0.f;
    const u16* g = GH + (size_t)r * 256 + q * 64;
    for (int c0 = 0; c0 < 64; c0 += 8) {
        uint4 u = *(const uint4*)&g[c0];
        u32 w[4] = {u.x, u.y, u.z, u.w};
#pragma unroll
        for (int p = 0; p < 4; ++p) {
            float f0 = h2f((u16)(w[p] & 0xFFFF));
            float f1 = h2f((u16)(w[p] >> 16));
            int c = q * 64 + c0 + p * 2;
            s0 += f0 * w2l[0][c] + f1 * w2l[0][c + 1];
            s1 += f0 * w2l[1][c] + f1 * w2l[1][c + 1];
            s2 += f0 * w2l[2][c] + f1 * w2l[2][c + 1];
        }
    }
    s0 += __shfl_xor(s0, 1); s0 += __shfl_xor(s0, 2);
    s1 += __shfl_xor(s1, 1); s1 += __shfl_xor(s1, 2);
    s2 += __shfl_xor(s2, 1); s2 += __shfl_xor(s2, 2);
    if (q == 0) {
        logits[(size_t)r * 3 + 0] = s0 + b2[0];
        logits[(size_t)r * 3 + 1] = s1 + b2[1];
        logits[(size_t)r * 3 + 2] = s2 + b2[2];
    }
}

// Repack conv weights p[o,d,j] (fp32) -> pk[t][j][o][d] (fp16)
__global__ void repack_p(const float* __restrict__ p1, const float* __restrict__ p2,
                         const float* __restrict__ p3, u16* __restrict__ pk)
{
    int idx = blockIdx.x * 256 + threadIdx.x;
    if (idx >= 3 * 3 * 512 * 512) return;
    int d = idx & 511;
    int oc = (idx >> 9) & 511;
    int j = (idx / (512 * 512)) % 3;
    int t = idx / (3 * 512 * 512);
    const float* p = (t == 0) ? p1 : (t == 1) ? p2 : p3;
    pk[idx] = f2h(p[(size_t)oc * 512 * 3 + (size_t)d * 3 + j]);
}

// ---------------------------------------------------------------------------
// Conv epilogue: outt[b][l][oc] = sum_{t,j} Cc[t][b*512+((l+j-1)%512)][j*512+oc]
// ---------------------------------------------------------------------------
__global__ __launch_bounds__(256) void conv_sum(
    const u16* __restrict__ Cc, float* __restrict__ outt)
{
    int gid = blockIdx.x * 256 + threadIdx.x;   // 524288 items
    int ocg = gid & 63;
    int r = gid >> 6;
    int b = r >> 9, l = r & 511;
    float s[8];
#pragma unroll
    for (int q = 0; q < 8; ++q) s[q] = 0.f;
#pragma unroll
    for (int t = 0; t < 3; ++t) {
#pragma unroll
        for (int j = 0; j < 3; ++j) {
            int lr = (l + j + 511) & 511;
            const u16x8 v = *(const u16x8*)&Cc[(size_t)t * 8192 * 1536 +
                ((size_t)(b * 512 + lr)) * 1536 + j * 512 + ocg * 8];
#pragma unroll
            for (int q = 0; q < 8; ++q) s[q] += h2f((u16)v[q]);
        }
    }
    float4 o0 = {s[0], s[1], s[2], s[3]};
    float4 o1 = {s[4], s[5], s[6], s[7]};
    *(float4*)&outt[(size_t)r * 512 + ocg * 8] = o0;
    *(float4*)&outt[(size_t)r * 512 + ocg * 8 + 4] = o1;
}

// ---------------------------------------------------------------------------
extern "C" void kernel_launch(void* const* d_in, const int* in_sizes, int n_in,
                              void* d_out, int out_size, void* d_ws, size_t ws_size,
                              hipStream_t stream)
{
    const float* x_in   = (const float*)d_in[0];
    const float* cross  = (const float*)d_in[1];
    const float* feb_wr = (const float*)d_in[2];
    const float* feb_wi = (const float*)d_in[3];
    const float* wq = (const float*)d_in[4];
    const float* bq = (const float*)d_in[5];
    const float* wk = (const float*)d_in[6];
    const float* bk = (const float*)d_in[7];
    const float* wv = (const float*)d_in[8];
    const float* bv = (const float*)d_in[9];
    const float* wo = (const float*)d_in[10];
    const float* bo = (const float*)d_in[11];
    const float* w_ff1 = (const float*)d_in[12];
    const float* w_ff2 = (const float*)d_in[13];
    const float* d1_w1 = (const float*)d_in[14];
    const float* d1_b1 = (const float*)d_in[15];
    const float* d1_w2 = (const float*)d_in[16];
    const float* d1_b2 = (const float*)d_in[17];
    const float* d2_w1 = (const float*)d_in[18];
    const float* d2_b1 = (const float*)d_in[19];
    const float* d2_w2 = (const float*)d_in[20];
    const float* d2_b2 = (const float*)d_in[21];
    const float* d3_w1 = (const float*)d_in[22];
    const float* d3_b1 = (const float*)d_in[23];
    const float* d3_w2 = (const float*)d_in[24];
    const float* d3_b2 = (const float*)d_in[25];
    const float* p1 = (const float*)d_in[26];
    const float* p2 = (const float*)d_in[27];
    const float* p3 = (const float*)d_in[28];

    // workspace (float offsets); end 42,427,392 floats = 169.7 MB
    float* ws = (float*)d_ws;
    float* X    = ws;                      // 4,194,304
    float* XT   = ws + 4194304;            // 4,194,304
    u16*  KVt   = (u16*)(ws + 8388608);    // [16][1024][1024] u16 = 8,388,608 f
    u16*  Q0t   = (u16*)(ws + 16777216);   // [16][512][512] u16 = 2,097,152 f
    u16*  T1h   = (u16*)(ws + 18874368);   // 2,097,152 f each; T1,T2,T3 contiguous
    u16*  T2h   = (u16*)(ws + 20971520);
    u16*  T3h   = (u16*)(ws + 23068672);
    float* QF   = ws + 25165824;           // [16][128][512] f32 = 1,048,576
    float* KVF  = ws + 26214400;           // [16][128][1024] f32 = 2,097,152
    u16*  OMTh  = (u16*)(ws + 28311552);   // [16][512][128] u16 = 524,288 f
    float* QTr  = ws + 28835840;           // 524,288
    float* QTi  = ws + 29360128;           // 524,288
    u16*  crossh = (u16*)(ws + 29884416);  // [16384][512] u16 = 4,194,304 f
    u16*  Xh    = (u16*)(ws + 34078720);   // 2,097,152 f
    u16*  XTh   = (u16*)(ws + 36175872);   // 2,097,152 f
    u16*  GHh   = (u16*)(ws + 38273024);   // 1,048,576 f
    float* GLG  = ws + 39321600;           // 24,576
    u16*  wqh   = (u16*)(ws + 39346176);   // u16 chain below
    u16*  wkvh  = wqh + 262144;            // 524,288 u16 ([wk; wv])
    u16*  woh   = wkvh + 524288;
    u16*  ff1h  = woh + 262144;            // 1,048,576 u16
    u16*  ff2h  = ff1h + 1048576;
    u16*  d1w1h = ff2h + 1048576;          // 131,072 u16 each
    u16*  d2w1h = d1w1h + 131072;
    u16*  d3w1h = d2w1h + 131072;
    u16*  PKh   = d3w1h + 131072;          // 2,359,296 u16 -> ends 42,295,296 f
    u16*  TW512h  = (u16*)(ws + 42295296); // 65,536 u16
    u16*  TW1024h = (u16*)(ws + 42328064); // 131,072 u16
    u16*  TIh     = (u16*)(ws + 42393600); // 65,536 u16
    float* bkv    = ws + 42426368;         // 1,024
    // overlays:
    float2* FEBP = (float2*)KVt;           // phase A partials (8 ch x 512 e x 16 b x 64 m float2 = 33.5 MB, fits KVt)
    u16*  xTh   = Q0t;                     // phase A xT (2,097,152 f region; Q0t written only in phase C)
    u16*  HIDh  = KVt;                     // phase E hidden (16,777,216 u16)
    u16*  Qh    = Q0t;                     // phase C post-attn overlay
    u16*  Cch   = (u16*)ws;                // phase G conv partials (37,748,736 u16)

    float* outx = (float*)d_out;
    float* outt = outx + 4194304;

    auto g128 = [&](const u16* A, const u16* W, const float* bias, const float* resid,
                    float* C, u16* Cb, int R, int N, int K, int flags,
                    int Z, u64 zsA, u64 zsW, u64 zsC, u64 zsR, int lrsh) {
        dim3 g(N / 128, R / 128, Z);
        hipLaunchKernelGGL(gemm_fp16, g, dim3(256), 0, stream,
                           A, W, bias, resid, C, Cb, R, N, K, flags, zsA, zsW, zsC, zsR, lrsh);
    };
    auto g64 = [&](const u16* A, const u16* W, const float* bias, const float* resid,
                   float* C, u16* Cb, int R, int N, int K, int flags,
                   int Z, u64 zsA, u64 zsW, u64 zsC, u64 zsR, int lrsh) {
        dim3 g(N / 64, R / 64, Z);
        hipLaunchKernelGGL(gemm64, g, dim3(256), 0, stream,
                           A, W, bias, resid, C, Cb, R, N, K, flags, zsA, zsW, zsC, zsR, lrsh);
    };

    // ---- Prep (single fused kernel) + conv-weight repack ----
    hipLaunchKernelGGL(prep, dim3(2048), dim3(256), 0, stream,
                       wq, wk, wv, wo, w_ff1, w_ff2, d1_w1, d2_w1, d3_w1, cross, bk, bv,
                       wqh, wkvh, woh, ff1h, ff2h, d1w1h, d2w1h, d3w1h, crossh, bkv,
                       TW512h, TW1024h, TIh);
    hipLaunchKernelGGL(repack_p, dim3(9216), dim3(256), 0, stream, p1, p2, p3, PKh);

    // ---- Phase A: x = x + fourier_block(x) ----
    hipLaunchKernelGGL(tr_cast_x, dim3(64, 16), dim3(256), 0, stream, x_in, xTh);
    g64(TW512h, xTh, nullptr, nullptr, QF, nullptr, 128, 512, 512, 16,
        16, 0, (u64)512 * 512, (u64)128 * 512, 0, 0);
    hipLaunchKernelGGL(spec_tr, dim3(8, 16), dim3(256), 0, stream, QF, QTr, QTi);
    hipLaunchKernelGGL(feb_part3, dim3(128, 8), dim3(256), 0, stream,
                       QTr, QTi, feb_wr, feb_wi, FEBP);
    hipLaunchKernelGGL(feb_reduce, dim3(2048), dim3(256), 0, stream, FEBP, OMTh);
    g64(TIh, OMTh, nullptr, x_in, X, Xh, 512, 512, 128, 16 | 8,
        16, 0, (u64)512 * 128, (u64)512 * 512, (u64)512 * 512, 0);

    // ---- Phase B: decomp1 ----
    g64(Xh, d1w1h, d1_b1, nullptr, nullptr, GHh, 8192, 256, 512, 1 | 8, 1, 0, 0, 0, 0, 0);
    hipLaunchKernelGGL(gate2, dim3(128), dim3(256), 0, stream, GHh, d1_w2, d1_b2, GLG);
    hipLaunchKernelGGL(decomp_apply, dim3(16384), dim3(256), 0, stream, X, GLG, XT, XTh, T1h);

    // ---- Phase C: x = x + fourier_cross(x, cross) ----
    g64(XTh, wqh, bq, nullptr, nullptr, Q0t, 8192, 512, 512, 32, 1, 0, 0, 0, 0, 9);
    g128(crossh, wkvh, bkv, nullptr, nullptr, KVt, 16384, 1024, 512, 32, 1, 0, 0, 0, 0, 10);
    g64(TW512h, Q0t, nullptr, nullptr, QF, nullptr, 128, 512, 512, 16,
        16, 0, (u64)512 * 512, (u64)128 * 512, 0, 0);
    g64(TW1024h, KVt, nullptr, nullptr, KVF, nullptr, 128, 1024, 1024, 16,
        16, 0, (u64)1024 * 1024, (u64)128 * 1024, 0, 0);
    hipLaunchKernelGGL(spectral_attn, dim3(128), dim3(256), 0, stream, QF, KVF, OMTh);
    g64(TIh, OMTh, nullptr, nullptr, nullptr, Qh, 512, 512, 128, 8,
        16, 0, (u64)512 * 128, (u64)512 * 512, 0, 0);
    g64(Qh, woh, bo, XT, X, Xh, 8192, 512, 512, 16 | 8, 1, 0, 0, 0, 0, 0);

    // ---- Phase D: decomp2 ----
    g64(Xh, d2w1h, d2_b1, nullptr, nullptr, GHh, 8192, 256, 512, 1 | 8, 1, 0, 0, 0, 0, 0);
    hipLaunchKernelGGL(gate2, dim3(128), dim3(256), 0, stream, GHh, d2_w2, d2_b2, GLG);
    hipLaunchKernelGGL(decomp_apply, dim3(16384), dim3(256), 0, stream, X, GLG, XT, XTh, T2h);

    // ---- Phase E: FFN ----
    g128(XTh, ff1h, nullptr, nullptr, nullptr, HIDh, 8192, 2048, 512, 1 | 8, 1, 0, 0, 0, 0, 0);
    g128(HIDh, ff2h, nullptr, XT, X, Xh, 8192, 512, 2048, 16 | 8, 1, 0, 0, 0, 0, 0);

    // ---- Phase F: decomp3 -> d_out x ----
    g64(Xh, d3w1h, d3_b1, nullptr, nullptr, GHh, 8192, 256, 512, 1 | 8, 1, 0, 0, 0, 0, 0);
    hipLaunchKernelGGL(gate2, dim3(128), dim3(256), 0, stream, GHh, d3_w2, d3_b2, GLG);
    hipLaunchKernelGGL(decomp_apply, dim3(16384), dim3(256), 0, stream, X, GLG, outx,
                       (u16*)nullptr, T3h);

    // ---- Phase G: conv partials (z=3 over t, N=1536 over j,oc) + shifted sum ----
    g128(T1h, PKh, nullptr, nullptr, nullptr, Cch, 8192, 1536, 512, 8,
         3, (u64)8192 * 512, (u64)1536 * 512, (u64)8192 * 1536, 0, 0);
    hipLaunchKernelGGL(conv_sum, dim3(2048), dim3(256), 0, stream, Cch, outt);

    (void)in_sizes; (void)n_in; (void)out_size; (void)ws_size;
}

// Round 9
// 530.189 us; speedup vs baseline: 1.8836x; 1.8836x over previous
//
#include <hip/hip_runtime.h>
#include <math.h>

typedef unsigned short u16;
typedef unsigned int u32;
typedef unsigned long long u64;

constexpr int kB = 16, kL = 512, kS = 1024, kD = 512, kM = 64;

typedef __attribute__((ext_vector_type(8))) short u16x8;
typedef __attribute__((ext_vector_type(8))) _Float16 f16x8;
typedef __attribute__((ext_vector_type(4))) float f32x4;

__device__ __forceinline__ u16 f2h(float f) {
    _Float16 h = (_Float16)f;
    return *(u16*)&h;
}
__device__ __forceinline__ float h2f(u16 u) {
    _Float16 h = *(_Float16*)&u;
    return (float)h;
}

// ---------------------------------------------------------------------------
// fp16 MFMA GEMM, z-batched: C[z][r,n] = op( sum_k A[z][r,k]*W[z][n,k] + .. )
// 128x128 tile, BK=64. flags: 1=relu, 8=fp16 Ch[r][n], 16=f32 Cout[r][n],
// 32=fp16 transposed Ch[b][n][l], b=r>>lrsh, l=r&((1<<lrsh)-1)
// ---------------------------------------------------------------------------
__global__ __launch_bounds__(256, 4) void gemm_fp16(
    const u16* __restrict__ Abase, const u16* __restrict__ Wbase,
    const float* __restrict__ bias, const float* __restrict__ resid,
    float* __restrict__ Cout, u16* __restrict__ Ch,
    int R, int N, int K, int flags,
    u64 zsA, u64 zsW, u64 zsC, u64 zsR, int lrsh)
{
    __shared__ __attribute__((aligned(16))) u16 Abuf[128 * 64];
    __shared__ __attribute__((aligned(16))) u16 Bbuf[128 * 64];
    const int zz = blockIdx.z;
    Abase += (u64)zz * zsA;
    Wbase += (u64)zz * zsW;
    if (Cout) Cout += (u64)zz * zsC;
    if (Ch)   Ch   += (u64)zz * zsC;
    if (resid) resid += (u64)zz * zsR;

    const int tid = threadIdx.x;
    const int lane = tid & 63;
    const int wave = tid >> 6;
    const int wr = wave >> 1, wc = wave & 1;
    const int ln15 = lane & 15, lq = lane >> 4;
    const int r0 = blockIdx.y * 128, n0 = blockIdx.x * 128;

    f32x4 acc[4][4];
#pragma unroll
    for (int m = 0; m < 4; ++m)
#pragma unroll
        for (int n = 0; n < 4; ++n) acc[m][n] = (f32x4){0.f, 0.f, 0.f, 0.f};

    for (int k0 = 0; k0 < K; k0 += 64) {
        u16x8 av[4], bv[4];
#pragma unroll
        for (int it = 0; it < 4; ++it) {
            int c = it * 256 + tid;
            int row = c >> 3, j = c & 7;
            int jj = j ^ (row & 7);
            av[it] = *(const u16x8*)(Abase + (size_t)(r0 + row) * K + k0 + jj * 8);
            bv[it] = *(const u16x8*)(Wbase + (size_t)(n0 + row) * K + k0 + jj * 8);
        }
        __syncthreads();
#pragma unroll
        for (int it = 0; it < 4; ++it) {
            int c = it * 256 + tid;
            int row = c >> 3, j = c & 7;
            *(u16x8*)&Abuf[row * 64 + j * 8] = av[it];
            *(u16x8*)&Bbuf[row * 64 + j * 8] = bv[it];
        }
        __syncthreads();
#pragma unroll
        for (int h = 0; h < 2; ++h) {
            int kg = lq + h * 4;
            f16x8 af[4], bfv[4];
#pragma unroll
            for (int m = 0; m < 4; ++m) {
                int row = wr * 64 + m * 16 + ln15;
                af[m] = *(const f16x8*)&Abuf[row * 64 + ((kg ^ (row & 7)) << 3)];
            }
#pragma unroll
            for (int n = 0; n < 4; ++n) {
                int col = wc * 64 + n * 16 + ln15;
                bfv[n] = *(const f16x8*)&Bbuf[col * 64 + ((kg ^ (col & 7)) << 3)];
            }
#pragma unroll
            for (int m = 0; m < 4; ++m)
#pragma unroll
                for (int n = 0; n < 4; ++n)
                    acc[m][n] = __builtin_amdgcn_mfma_f32_16x16x32_f16(af[m], bfv[n], acc[m][n], 0, 0, 0);
        }
        __syncthreads();
    }

#pragma unroll
    for (int m = 0; m < 4; ++m) {
#pragma unroll
        for (int n = 0; n < 4; ++n) {
            int gc = n0 + wc * 64 + n * 16 + ln15;
            float bv_ = bias ? bias[gc] : 0.f;
            int gr0 = r0 + wr * 64 + m * 16 + lq * 4;
            float v[4];
#pragma unroll
            for (int rg = 0; rg < 4; ++rg) {
                int gr = gr0 + rg;
                float val = acc[m][n][rg] + bv_;
                if (resid) val += resid[(size_t)gr * N + gc];
                if (flags & 1) val = fmaxf(val, 0.f);
                if (flags & 16) Cout[(size_t)gr * N + gc] = val;
                if (flags & 8)  Ch[(size_t)gr * N + gc] = f2h(val);
                v[rg] = val;
            }
            if (flags & 32) {
                int bb = gr0 >> lrsh;
                int l_ = gr0 & ((1 << lrsh) - 1);
                ushort4 o;
                o.x = f2h(v[0]); o.y = f2h(v[1]); o.z = f2h(v[2]); o.w = f2h(v[3]);
                *(ushort4*)&Ch[(((size_t)bb * N + gc) << lrsh) + l_] = o;
            }
        }
    }
}

// ---------------------------------------------------------------------------
// 64x64-tile fp16 GEMM for thin/batched shapes. Same flags as gemm_fp16.
// ---------------------------------------------------------------------------
__global__ __launch_bounds__(256, 4) void gemm64(
    const u16* __restrict__ Abase, const u16* __restrict__ Wbase,
    const float* __restrict__ bias, const float* __restrict__ resid,
    float* __restrict__ Cout, u16* __restrict__ Ch,
    int R, int N, int K, int flags,
    u64 zsA, u64 zsW, u64 zsC, u64 zsR, int lrsh)
{
    __shared__ __attribute__((aligned(16))) u16 Abuf[64 * 64];
    __shared__ __attribute__((aligned(16))) u16 Bbuf[64 * 64];
    const int zz = blockIdx.z;
    Abase += (u64)zz * zsA;
    Wbase += (u64)zz * zsW;
    if (Cout) Cout += (u64)zz * zsC;
    if (Ch)   Ch   += (u64)zz * zsC;
    if (resid) resid += (u64)zz * zsR;

    const int tid = threadIdx.x;
    const int lane = tid & 63;
    const int w = tid >> 6;
    const int ln15 = lane & 15, lq = lane >> 4;
    const int r0 = blockIdx.y * 64, n0 = blockIdx.x * 64;

    f32x4 acc[4];
#pragma unroll
    for (int m = 0; m < 4; ++m) acc[m] = (f32x4){0.f, 0.f, 0.f, 0.f};

    for (int k0 = 0; k0 < K; k0 += 64) {
        u16x8 av[2], bv[2];
#pragma unroll
        for (int it = 0; it < 2; ++it) {
            int c = it * 256 + tid;
            int row = c >> 3, j = c & 7;
            int jj = j ^ (row & 7);
            av[it] = *(const u16x8*)(Abase + (size_t)(r0 + row) * K + k0 + jj * 8);
            bv[it] = *(const u16x8*)(Wbase + (size_t)(n0 + row) * K + k0 + jj * 8);
        }
        __syncthreads();
#pragma unroll
        for (int it = 0; it < 2; ++it) {
            int c = it * 256 + tid;
            int row = c >> 3, j = c & 7;
            *(u16x8*)&Abuf[row * 64 + j * 8] = av[it];
            *(u16x8*)&Bbuf[row * 64 + j * 8] = bv[it];
        }
        __syncthreads();
#pragma unroll
        for (int h = 0; h < 2; ++h) {
            int kg = lq + h * 4;
            int col = w * 16 + ln15;
            f16x8 bf = *(const f16x8*)&Bbuf[col * 64 + ((kg ^ (col & 7)) << 3)];
#pragma unroll
            for (int m = 0; m < 4; ++m) {
                int row = m * 16 + ln15;
                f16x8 af = *(const f16x8*)&Abuf[row * 64 + ((kg ^ (row & 7)) << 3)];
                acc[m] = __builtin_amdgcn_mfma_f32_16x16x32_f16(af, bf, acc[m], 0, 0, 0);
            }
        }
        __syncthreads();
    }

    const int gc = n0 + w * 16 + ln15;
    const float bv_ = bias ? bias[gc] : 0.f;
#pragma unroll
    for (int m = 0; m < 4; ++m) {
        int gr0 = r0 + m * 16 + lq * 4;
        float v[4];
#pragma unroll
        for (int rg = 0; rg < 4; ++rg) {
            int gr = gr0 + rg;
            float val = acc[m][rg] + bv_;
            if (resid) val += resid[(size_t)gr * N + gc];
            if (flags & 1) val = fmaxf(val, 0.f);
            if (flags & 16) Cout[(size_t)gr * N + gc] = val;
            if (flags & 8)  Ch[(size_t)gr * N + gc] = f2h(val);
            v[rg] = val;
        }
        if (flags & 32) {
            int bb = gr0 >> lrsh;
            int l_ = gr0 & ((1 << lrsh) - 1);
            ushort4 o;
            o.x = f2h(v[0]); o.y = f2h(v[1]); o.z = f2h(v[2]); o.w = f2h(v[3]);
            *(ushort4*)&Ch[(((size_t)bb * N + gc) << lrsh) + l_] = o;
        }
    }
}

// ---------------------------------------------------------------------------
// Fused prep: all weight casts, K|V weight/bias concat, cross cast, twiddles.
// ---------------------------------------------------------------------------
__global__ __launch_bounds__(256) void prep(
    const float* __restrict__ wq, const float* __restrict__ wk,
    const float* __restrict__ wv, const float* __restrict__ wo,
    const float* __restrict__ ff1, const float* __restrict__ ff2,
    const float* __restrict__ dw1, const float* __restrict__ dw2,
    const float* __restrict__ dw3, const float* __restrict__ cross,
    const float* __restrict__ bk, const float* __restrict__ bv,
    u16* __restrict__ wqh, u16* __restrict__ wkvh, u16* __restrict__ woh,
    u16* __restrict__ ff1h, u16* __restrict__ ff2h,
    u16* __restrict__ d1w1h, u16* __restrict__ d2w1h, u16* __restrict__ d3w1h,
    u16* __restrict__ crossh, float* __restrict__ bkv,
    u16* __restrict__ tw512, u16* __restrict__ tw1024, u16* __restrict__ tih)
{
    const int gid = blockIdx.x * 256 + threadIdx.x;
    const int stride = gridDim.x * 256;
    for (int i = gid; i < 262144; i += stride) wqh[i] = f2h(wq[i]);
    for (int i = gid; i < 262144; i += stride) wkvh[i] = f2h(wk[i]);
    for (int i = gid; i < 262144; i += stride) wkvh[262144 + i] = f2h(wv[i]);
    for (int i = gid; i < 262144; i += stride) woh[i] = f2h(wo[i]);
    for (int i = gid; i < 1048576; i += stride) ff1h[i] = f2h(ff1[i]);
    for (int i = gid; i < 1048576; i += stride) ff2h[i] = f2h(ff2[i]);
    for (int i = gid; i < 131072; i += stride) d1w1h[i] = f2h(dw1[i]);
    for (int i = gid; i < 131072; i += stride) d2w1h[i] = f2h(dw2[i]);
    for (int i = gid; i < 131072; i += stride) d3w1h[i] = f2h(dw3[i]);
    const float4* c4 = (const float4*)cross;
    for (int i = gid; i < 2097152; i += stride) {
        float4 v = c4[i];
        ushort4 o;
        o.x = f2h(v.x); o.y = f2h(v.y); o.z = f2h(v.z); o.w = f2h(v.w);
        *(ushort4*)&crossh[i * 4] = o;
    }
    for (int i = gid; i < 1024; i += stride) bkv[i] = (i < 512) ? bk[i] : bv[i - 512];
    for (int i = gid; i < 65536; i += stride) {
        int r = i >> 9, l = i & 511;
        int m = r & 63;
        int ph = (m * l) & 511;
        float ang = 6.283185307179586f * (float)ph / 512.0f;
        float s_, c_;
        sincosf(ang, &s_, &c_);
        tw512[i] = f2h((r < 64) ? c_ : -s_);
    }
    for (int i = gid; i < 131072; i += stride) {
        int r = i >> 10, l = i & 1023;
        int m = r & 63;
        int ph = (m * l) & 1023;
        float ang = 6.283185307179586f * (float)ph / 1024.0f;
        float s_, c_;
        sincosf(ang, &s_, &c_);
        tw1024[i] = f2h((r < 64) ? c_ : -s_);
    }
    for (int i = gid; i < 65536; i += stride) {
        int l = i >> 7, r = i & 127;
        int m = r & 63;
        int ph = (m * l) & 511;
        float ang = 6.283185307179586f * (float)ph / 512.0f;
        float s_, c_;
        sincosf(ang, &s_, &c_);
        float val;
        if (r == 0) val = 1.0f / 512.0f;
        else if (r < 64) val = 2.0f * c_ / 512.0f;
        else if (r == 64) val = 0.0f;
        else val = -2.0f * s_ / 512.0f;
        tih[i] = f2h(val);
    }
}

// ---------------------------------------------------------------------------
// Transpose+cast x[b][l][d] fp32 -> xT[b][d][l] fp16. 64x64 LDS tiles.
// ---------------------------------------------------------------------------
__global__ __launch_bounds__(256) void tr_cast_x(
    const float* __restrict__ x, u16* __restrict__ xt)
{
    __shared__ u16 t[64][72];
    const int b = blockIdx.y;
    const int lt = (blockIdx.x >> 3) * 64, dt = (blockIdx.x & 7) * 64;
    const int tid = threadIdx.x;
#pragma unroll
    for (int rep = 0; rep < 16; ++rep) {
        int idx = tid + rep * 256;
        int row = idx >> 6, col = idx & 63;
        t[row][col] = f2h(x[((size_t)b * kL + lt + row) * kD + dt + col]);
    }
    __syncthreads();
#pragma unroll
    for (int rep = 0; rep < 16; ++rep) {
        int idx = tid + rep * 256;
        int row = idx >> 6, col = idx & 63;
        xt[((size_t)b * kD + dt + row) * kL + lt + col] = t[col][row];
    }
}

// ---------------------------------------------------------------------------
// Spectral transpose for FEB: QF[b][128][512] fp32 -> QTr/QTi [d][b][m] fp32.
// ---------------------------------------------------------------------------
__global__ __launch_bounds__(256) void spec_tr(
    const float* __restrict__ QF, float* __restrict__ qtr, float* __restrict__ qti)
{
    __shared__ float t0[64][65], t1[64][65];
    const int b = blockIdx.y;
    const int dt = blockIdx.x * 64;
    const int tid = threadIdx.x;
    const float* QFb = QF + (size_t)b * 128 * 512;
#pragma unroll
    for (int rep = 0; rep < 16; ++rep) {
        int idx = tid + rep * 256;
        int m = idx >> 6, dd = idx & 63;
        t0[m][dd] = QFb[(size_t)m * 512 + dt + dd];
        t1[m][dd] = QFb[(size_t)(64 + m) * 512 + dt + dd];
    }
    __syncthreads();
#pragma unroll
    for (int rep = 0; rep < 16; ++rep) {
        int idx = tid + rep * 256;
        int dd = idx >> 6, m = idx & 63;
        size_t o = ((size_t)(dt + dd) * kB + b) * kM + m;
        qtr[o] = t0[m][dd];
        qti[o] = t1[m][dd];
    }
}

// ---------------------------------------------------------------------------
// FEB per-mode contraction, d-chunked partials. EXACT round-6 version
// (known-good: 104 us, no spill). Do not perturb.
// ---------------------------------------------------------------------------
__global__ __launch_bounds__(256) void feb_part(
    const float* __restrict__ qtr, const float* __restrict__ qti,
    const float* __restrict__ wr, const float* __restrict__ wi,
    float* __restrict__ part)
{
    __shared__ float sqr[4][16][64], sqi[4][16][64];
    const int eb = blockIdx.x;
    const int ch = blockIdx.y;
    const int tid = threadIdx.x;
    const int mm = tid & 63, ee = tid >> 6;
    const int e = eb * 4 + ee;
    float ar[16], ai[16];
#pragma unroll
    for (int b_ = 0; b_ < 16; ++b_) { ar[b_] = 0.f; ai[b_] = 0.f; }

    const int dbeg = ch * 128, dend = dbeg + 128;
    for (int d0 = dbeg; d0 < dend; d0 += 4) {
        __syncthreads();
#pragma unroll
        for (int rep = 0; rep < 16; ++rep) {
            int idx = tid + rep * 256;
            int m_ = idx & 63, b_ = (idx >> 6) & 15, dd_ = idx >> 10;
            size_t g = ((size_t)(d0 + dd_) * kB + b_) * kM + m_;
            sqr[dd_][b_][m_] = qtr[g];
            sqi[dd_][b_][m_] = qti[g];
        }
        __syncthreads();
#pragma unroll
        for (int dd = 0; dd < 4; ++dd) {
            size_t wofs = ((size_t)(d0 + dd) * kD + e) * kM + mm;
            float wrv = wr[wofs], wiv = wi[wofs];
#pragma unroll
            for (int b_ = 0; b_ < 16; ++b_) {
                float qr = sqr[dd][b_][mm], qi = sqi[dd][b_][mm];
                ar[b_] += qr * wrv - qi * wiv;
                ai[b_] += qr * wiv + qi * wrv;
            }
        }
    }
    float* reg = part + (size_t)(ch * 128 + eb) * 8192;
#pragma unroll
    for (int b_ = 0; b_ < 16; ++b_) {
        reg[(b_ * 64 + mm) * 4 + ee] = ar[b_];
        reg[4096 + (b_ * 64 + mm) * 4 + ee] = ai[b_];
    }
}

// Reduce partials -> OMT fp16 [b][e][r] (r<64 real, r>=64 imag). Round-6 exact.
__global__ __launch_bounds__(256) void feb_reduce(
    const float* __restrict__ part, u16* __restrict__ OMT)
{
    int idx = blockIdx.x * 256 + threadIdx.x;   // 0..524287
    int m = idx & 63, e = (idx >> 6) & 511, b = idx >> 15;
    int eb = e >> 2, ee = e & 3;
    float r = 0.f, im = 0.f;
#pragma unroll
    for (int ch = 0; ch < 4; ++ch) {
        const float* reg = part + (size_t)(ch * 128 + eb) * 8192 + ((b * 64 + m) * 4 + ee);
        r += reg[0];
        im += reg[4096];
    }
    u16* o = OMT + ((size_t)(b * 512 + e)) * 128;
    o[m] = f2h(r);
    o[64 + m] = f2h(im);
}

// ---------------------------------------------------------------------------
// Spectral cross attention, one block per (b,h). QF fp32 [b][128][512];
// KVF fp32 [b][128][1024]. Output OMT fp16 [b][e][r].
// ---------------------------------------------------------------------------
__global__ __launch_bounds__(256) void spectral_attn(
    const float* __restrict__ QF, const float* __restrict__ KVF,
    u16* __restrict__ OMT)
{
    __shared__ float kr[64][65], ki[64][65], sat[64][65];
    const int b = blockIdx.x >> 3, h = blockIdx.x & 7;
    const int tid = threadIdx.x;
    const int dbase = h * 64;
    const float* KVFb = KVF + (size_t)b * 128 * 1024;

    for (int idx = tid; idx < 4096; idx += 256) {
        int j = idx >> 6, dd = idx & 63;
        kr[j][dd] = KVFb[(size_t)j * 1024 + dbase + dd];
        ki[j][dd] = KVFb[(size_t)(64 + j) * 1024 + dbase + dd];
    }
    __syncthreads();

    const int i_ = tid >> 2, jg = tid & 3;
    float s[16];
#pragma unroll
    for (int jj = 0; jj < 16; ++jj) s[jj] = 0.f;
    const float* qrp = QF + ((size_t)b * 128 + i_) * 512 + dbase;
    const float* qip = qrp + (size_t)64 * 512;
    for (int dd = 0; dd < 64; ++dd) {
        float qr = qrp[dd], qi = qip[dd];
#pragma unroll
        for (int jj = 0; jj < 16; ++jj) {
            int j = jg * 16 + jj;
            s[jj] += qr * kr[j][dd] + qi * ki[j][dd];
        }
    }
    float mx = s[0];
#pragma unroll
    for (int jj = 1; jj < 16; ++jj) mx = fmaxf(mx, s[jj]);
    mx = fmaxf(mx, __shfl_xor(mx, 1));
    mx = fmaxf(mx, __shfl_xor(mx, 2));
    float sum = 0.f;
#pragma unroll
    for (int jj = 0; jj < 16; ++jj) { s[jj] = expf(s[jj] - mx); sum += s[jj]; }
    sum += __shfl_xor(sum, 1);
    sum += __shfl_xor(sum, 2);
    float rinv = 1.0f / sum;
#pragma unroll
    for (int jj = 0; jj < 16; ++jj) sat[i_][jg * 16 + jj] = s[jj] * rinv;
    __syncthreads();

    const int dd = tid & 63, ig = tid >> 6;
    float ar[16], ai[16];
#pragma unroll
    for (int ii = 0; ii < 16; ++ii) { ar[ii] = 0.f; ai[ii] = 0.f; }
    const float* VFb = KVFb + 512 + dbase + dd;
    for (int j = 0; j < 64; ++j) {
        float vr = VFb[(size_t)j * 1024];
        float vi = VFb[(size_t)(64 + j) * 1024];
#pragma unroll
        for (int ii = 0; ii < 16; ++ii) {
            float a = sat[ig * 16 + ii][j];
            ar[ii] += a * vr;
            ai[ii] += a * vi;
        }
    }
    u16* o = OMT + ((size_t)(b * 512 + dbase + dd)) * 128 + ig * 16;
    u16x8 v0, v1, w0, w1;
#pragma unroll
    for (int q = 0; q < 8; ++q) {
        v0[q] = (short)f2h(ar[q]);     v1[q] = (short)f2h(ar[8 + q]);
        w0[q] = (short)f2h(ai[q]);     w1[q] = (short)f2h(ai[8 + q]);
    }
    *(u16x8*)(o) = v0;
    *(u16x8*)(o + 8) = v1;
    *(u16x8*)(o + 64) = w0;
    *(u16x8*)(o + 72) = w1;
}

// ---------------------------------------------------------------------------
// MoE decomposition epilogue.
// ---------------------------------------------------------------------------
__global__ __launch_bounds__(256) void decomp_apply(
    const float* __restrict__ x, const float* __restrict__ logits,
    float* __restrict__ xout, u16* __restrict__ xout_h, u16* __restrict__ tout_h)
{
    int idx = blockIdx.x * 256 + threadIdx.x;
    if (idx >= kB * kL * kD) return;
    int d = idx & 511;
    int l = (idx >> 9) & 511;
    int b = idx >> 18;
    const float* lg = logits + ((size_t)b * kL + l) * 3;
    float g0 = lg[0], g1 = lg[1], g2 = lg[2];
    float m = fmaxf(g0, fmaxf(g1, g2));
    float e0 = expf(g0 - m), e1 = expf(g1 - m), e2 = expf(g2 - m);
    float inv = 1.0f / (e0 + e1 + e2);
    g0 = e0 * inv; g1 = e1 * inv; g2 = e2 * inv;

    const float* xb = x + (size_t)b * kL * kD + d;
    float v[7];
#pragma unroll
    for (int j = 0; j < 7; ++j) {
        int ls = l + j - 3;
        v[j] = (ls >= 0 && ls < kL) ? xb[(size_t)ls * kD] : 0.f;
    }
    float s3 = (v[2] + v[3] + v[4]) * (1.0f / 3.0f);
    float s5 = (v[1] + v[2] + v[3] + v[4] + v[5]) * 0.2f;
    float s7 = (v[0] + v[1] + v[2] + v[3] + v[4] + v[5] + v[6]) * (1.0f / 7.0f);
    float trend = g0 * s3 + g1 * s5 + g2 * s7;
    float res = v[3] - trend;
    if (xout) xout[idx] = res;
    if (xout_h) xout_h[idx] = f2h(res);
    tout_h[idx] = f2h(trend);
}

// ---------------------------------------------------------------------------
// Gate layer 2, K-quarter split: thread (row, q); shuffle-combine over quad.
// grid 128 x 256.
// ---------------------------------------------------------------------------
__global__ __launch_bounds__(256) void gate2(
    const u16* __restrict__ GH, const float* __restrict__ w2,
    const float* __restrict__ b2, float* __restrict__ logits)
{
    __shared__ float w2l[3][256];
    int tid = threadIdx.x;
    for (int i = tid; i < 768; i += 256) w2l[i >> 8][i & 255] = w2[i];
    __syncthreads();
    int gid = blockIdx.x * 256 + tid;
    int r = gid >> 2, q = gid & 3;
    float s0 = 0.f, s1 = 0.f, s2 = 0.f;
    const u16* g = GH + (size_t)r * 256 + q * 64;
    for (int c0 = 0; c0 < 64; c0 += 8) {
        uint4 u = *(const uint4*)&g[c0];
        u32 w[4] = {u.x, u.y, u.z, u.w};
#pragma unroll
        for (int p = 0; p < 4; ++p) {
            float f0 = h2f((u16)(w[p] & 0xFFFF));
            float f1 = h2f((u16)(w[p] >> 16));
            int c = q * 64 + c0 + p * 2;
            s0 += f0 * w2l[0][c] + f1 * w2l[0][c + 1];
            s1 += f0 * w2l[1][c] + f1 * w2l[1][c + 1];
            s2 += f0 * w2l[2][c] + f1 * w2l[2][c + 1];
        }
    }
    s0 += __shfl_xor(s0, 1); s0 += __shfl_xor(s0, 2);
    s1 += __shfl_xor(s1, 1); s1 += __shfl_xor(s1, 2);
    s2 += __shfl_xor(s2, 1); s2 += __shfl_xor(s2, 2);
    if (q == 0) {
        logits[(size_t)r * 3 + 0] = s0 + b2[0];
        logits[(size_t)r * 3 + 1] = s1 + b2[1];
        logits[(size_t)r * 3 + 2] = s2 + b2[2];
    }
}

// Repack conv weights p[o,d,j] (fp32) -> pk[t][j][o][d] (fp16)
__global__ void repack_p(const float* __restrict__ p1, const float* __restrict__ p2,
                         const float* __restrict__ p3, u16* __restrict__ pk)
{
    int idx = blockIdx.x * 256 + threadIdx.x;
    if (idx >= 3 * 3 * 512 * 512) return;
    int d = idx & 511;
    int oc = (idx >> 9) & 511;
    int j = (idx / (512 * 512)) % 3;
    int t = idx / (3 * 512 * 512);
    const float* p = (t == 0) ? p1 : (t == 1) ? p2 : p3;
    pk[idx] = f2h(p[(size_t)oc * 512 * 3 + (size_t)d * 3 + j]);
}

// ---------------------------------------------------------------------------
// Conv epilogue: outt[b][l][oc] = sum_{t,j} Cc[t][b*512+((l+j-1)%512)][j*512+oc]
// ---------------------------------------------------------------------------
__global__ __launch_bounds__(256) void conv_sum(
    const u16* __restrict__ Cc, float* __restrict__ outt)
{
    int gid = blockIdx.x * 256 + threadIdx.x;   // 524288 items
    int ocg = gid & 63;
    int r = gid >> 6;
    int b = r >> 9, l = r & 511;
    float s[8];
#pragma unroll
    for (int q = 0; q < 8; ++q) s[q] = 0.f;
#pragma unroll
    for (int t = 0; t < 3; ++t) {
#pragma unroll
        for (int j = 0; j < 3; ++j) {
            int lr = (l + j + 511) & 511;
            const u16x8 v = *(const u16x8*)&Cc[(size_t)t * 8192 * 1536 +
                ((size_t)(b * 512 + lr)) * 1536 + j * 512 + ocg * 8];
#pragma unroll
            for (int q = 0; q < 8; ++q) s[q] += h2f((u16)v[q]);
        }
    }
    float4 o0 = {s[0], s[1], s[2], s[3]};
    float4 o1 = {s[4], s[5], s[6], s[7]};
    *(float4*)&outt[(size_t)r * 512 + ocg * 8] = o0;
    *(float4*)&outt[(size_t)r * 512 + ocg * 8 + 4] = o1;
}

// ---------------------------------------------------------------------------
extern "C" void kernel_launch(void* const* d_in, const int* in_sizes, int n_in,
                              void* d_out, int out_size, void* d_ws, size_t ws_size,
                              hipStream_t stream)
{
    const float* x_in   = (const float*)d_in[0];
    const float* cross  = (const float*)d_in[1];
    const float* feb_wr = (const float*)d_in[2];
    const float* feb_wi = (const float*)d_in[3];
    const float* wq = (const float*)d_in[4];
    const float* bq = (const float*)d_in[5];
    const float* wk = (const float*)d_in[6];
    const float* bk = (const float*)d_in[7];
    const float* wv = (const float*)d_in[8];
    const float* bv = (const float*)d_in[9];
    const float* wo = (const float*)d_in[10];
    const float* bo = (const float*)d_in[11];
    const float* w_ff1 = (const float*)d_in[12];
    const float* w_ff2 = (const float*)d_in[13];
    const float* d1_w1 = (const float*)d_in[14];
    const float* d1_b1 = (const float*)d_in[15];
    const float* d1_w2 = (const float*)d_in[16];
    const float* d1_b2 = (const float*)d_in[17];
    const float* d2_w1 = (const float*)d_in[18];
    const float* d2_b1 = (const float*)d_in[19];
    const float* d2_w2 = (const float*)d_in[20];
    const float* d2_b2 = (const float*)d_in[21];
    const float* d3_w1 = (const float*)d_in[22];
    const float* d3_b1 = (const float*)d_in[23];
    const float* d3_w2 = (const float*)d_in[24];
    const float* d3_b2 = (const float*)d_in[25];
    const float* p1 = (const float*)d_in[26];
    const float* p2 = (const float*)d_in[27];
    const float* p3 = (const float*)d_in[28];

    // workspace (float offsets); end 42,427,392 floats = 169.7 MB
    float* ws = (float*)d_ws;
    float* X    = ws;                      // 4,194,304
    float* XT   = ws + 4194304;            // 4,194,304
    u16*  KVt   = (u16*)(ws + 8388608);    // [16][1024][1024] u16 = 8,388,608 f
    u16*  Q0t   = (u16*)(ws + 16777216);   // [16][512][512] u16 = 2,097,152 f
    u16*  T1h   = (u16*)(ws + 18874368);   // 2,097,152 f each; T1,T2,T3 contiguous
    u16*  T2h   = (u16*)(ws + 20971520);
    u16*  T3h   = (u16*)(ws + 23068672);
    float* QF   = ws + 25165824;           // [16][128][512] f32 = 1,048,576
    float* KVF  = ws + 26214400;           // [16][128][1024] f32 = 2,097,152
    u16*  OMTh  = (u16*)(ws + 28311552);   // [16][512][128] u16 = 524,288 f
    float* QTr  = ws + 28835840;           // 524,288
    float* QTi  = ws + 29360128;           // 524,288
    u16*  crossh = (u16*)(ws + 29884416);  // [16384][512] u16 = 4,194,304 f
    u16*  Xh    = (u16*)(ws + 34078720);   // 2,097,152 f
    u16*  XTh   = (u16*)(ws + 36175872);   // 2,097,152 f
    u16*  GHh   = (u16*)(ws + 38273024);   // 1,048,576 f
    float* GLG  = ws + 39321600;           // 24,576
    u16*  wqh   = (u16*)(ws + 39346176);   // u16 chain below
    u16*  wkvh  = wqh + 262144;            // 524,288 u16 ([wk; wv])
    u16*  woh   = wkvh + 524288;
    u16*  ff1h  = woh + 262144;            // 1,048,576 u16
    u16*  ff2h  = ff1h + 1048576;
    u16*  d1w1h = ff2h + 1048576;          // 131,072 u16 each
    u16*  d2w1h = d1w1h + 131072;
    u16*  d3w1h = d2w1h + 131072;
    u16*  PKh   = d3w1h + 131072;          // 2,359,296 u16 -> ends 42,295,296 f
    u16*  TW512h  = (u16*)(ws + 42295296); // 65,536 u16
    u16*  TW1024h = (u16*)(ws + 42328064); // 131,072 u16
    u16*  TIh     = (u16*)(ws + 42393600); // 65,536 u16
    float* bkv    = ws + 42426368;         // 1,024
    // overlays (round-6 layout):
    float* FEBP = (float*)KVt;             // phase A partials: 512 regions x 8192 f = 16 MB (first half of KVt)
    u16*  xTh   = (u16*)(ws + 12582912);   // phase A xT ([16][512][512] u16, second half of KVt region)
    u16*  HIDh  = KVt;                     // phase E hidden (16,777,216 u16)
    u16*  Qh    = Q0t;                     // phase C post-attn overlay
    u16*  Cch   = (u16*)ws;                // phase G conv partials (37,748,736 u16)

    float* outx = (float*)d_out;
    float* outt = outx + 4194304;

    auto g128 = [&](const u16* A, const u16* W, const float* bias, const float* resid,
                    float* C, u16* Cb, int R, int N, int K, int flags,
                    int Z, u64 zsA, u64 zsW, u64 zsC, u64 zsR, int lrsh) {
        dim3 g(N / 128, R / 128, Z);
        hipLaunchKernelGGL(gemm_fp16, g, dim3(256), 0, stream,
                           A, W, bias, resid, C, Cb, R, N, K, flags, zsA, zsW, zsC, zsR, lrsh);
    };
    auto g64 = [&](const u16* A, const u16* W, const float* bias, const float* resid,
                   float* C, u16* Cb, int R, int N, int K, int flags,
                   int Z, u64 zsA, u64 zsW, u64 zsC, u64 zsR, int lrsh) {
        dim3 g(N / 64, R / 64, Z);
        hipLaunchKernelGGL(gemm64, g, dim3(256), 0, stream,
                           A, W, bias, resid, C, Cb, R, N, K, flags, zsA, zsW, zsC, zsR, lrsh);
    };

    // ---- Prep (single fused kernel) + conv-weight repack ----
    hipLaunchKernelGGL(prep, dim3(2048), dim3(256), 0, stream,
                       wq, wk, wv, wo, w_ff1, w_ff2, d1_w1, d2_w1, d3_w1, cross, bk, bv,
                       wqh, wkvh, woh, ff1h, ff2h, d1w1h, d2w1h, d3w1h, crossh, bkv,
                       TW512h, TW1024h, TIh);
    hipLaunchKernelGGL(repack_p, dim3(9216), dim3(256), 0, stream, p1, p2, p3, PKh);

    // ---- Phase A: x = x + fourier_block(x) ----
    hipLaunchKernelGGL(tr_cast_x, dim3(64, 16), dim3(256), 0, stream, x_in, xTh);
    g64(TW512h, xTh, nullptr, nullptr, QF, nullptr, 128, 512, 512, 16,
        16, 0, (u64)512 * 512, (u64)128 * 512, 0, 0);
    hipLaunchKernelGGL(spec_tr, dim3(8, 16), dim3(256), 0, stream, QF, QTr, QTi);
    hipLaunchKernelGGL(feb_part, dim3(128, 4), dim3(256), 0, stream,
                       QTr, QTi, feb_wr, feb_wi, FEBP);
    hipLaunchKernelGGL(feb_reduce, dim3(2048), dim3(256), 0, stream, FEBP, OMTh);
    g64(TIh, OMTh, nullptr, x_in, X, Xh, 512, 512, 128, 16 | 8,
        16, 0, (u64)512 * 128, (u64)512 * 512, (u64)512 * 512, 0);

    // ---- Phase B: decomp1 ----
    g64(Xh, d1w1h, d1_b1, nullptr, nullptr, GHh, 8192, 256, 512, 1 | 8, 1, 0, 0, 0, 0, 0);
    hipLaunchKernelGGL(gate2, dim3(128), dim3(256), 0, stream, GHh, d1_w2, d1_b2, GLG);
    hipLaunchKernelGGL(decomp_apply, dim3(16384), dim3(256), 0, stream, X, GLG, XT, XTh, T1h);

    // ---- Phase C: x = x + fourier_cross(x, cross) ----
    g64(XTh, wqh, bq, nullptr, nullptr, Q0t, 8192, 512, 512, 32, 1, 0, 0, 0, 0, 9);
    g128(crossh, wkvh, bkv, nullptr, nullptr, KVt, 16384, 1024, 512, 32, 1, 0, 0, 0, 0, 10);
    g64(TW512h, Q0t, nullptr, nullptr, QF, nullptr, 128, 512, 512, 16,
        16, 0, (u64)512 * 512, (u64)128 * 512, 0, 0);
    g64(TW1024h, KVt, nullptr, nullptr, KVF, nullptr, 128, 1024, 1024, 16,
        16, 0, (u64)1024 * 1024, (u64)128 * 1024, 0, 0);
    hipLaunchKernelGGL(spectral_attn, dim3(128), dim3(256), 0, stream, QF, KVF, OMTh);
    g64(TIh, OMTh, nullptr, nullptr, nullptr, Qh, 512, 512, 128, 8,
        16, 0, (u64)512 * 128, (u64)512 * 512, 0, 0);
    g64(Qh, woh, bo, XT, X, Xh, 8192, 512, 512, 16 | 8, 1, 0, 0, 0, 0, 0);

    // ---- Phase D: decomp2 ----
    g64(Xh, d2w1h, d2_b1, nullptr, nullptr, GHh, 8192, 256, 512, 1 | 8, 1, 0, 0, 0, 0, 0);
    hipLaunchKernelGGL(gate2, dim3(128), dim3(256), 0, stream, GHh, d2_w2, d2_b2, GLG);
    hipLaunchKernelGGL(decomp_apply, dim3(16384), dim3(256), 0, stream, X, GLG, XT, XTh, T2h);

    // ---- Phase E: FFN (FFN2 now on gemm64 for 4x grid width) ----
    g128(XTh, ff1h, nullptr, nullptr, nullptr, HIDh, 8192, 2048, 512, 1 | 8, 1, 0, 0, 0, 0, 0);
    g64(HIDh, ff2h, nullptr, XT, X, Xh, 8192, 512, 2048, 16 | 8, 1, 0, 0, 0, 0, 0);

    // ---- Phase F: decomp3 -> d_out x ----
    g64(Xh, d3w1h, d3_b1, nullptr, nullptr, GHh, 8192, 256, 512, 1 | 8, 1, 0, 0, 0, 0, 0);
    hipLaunchKernelGGL(gate2, dim3(128), dim3(256), 0, stream, GHh, d3_w2, d3_b2, GLG);
    hipLaunchKernelGGL(decomp_apply, dim3(16384), dim3(256), 0, stream, X, GLG, outx,
                       (u16*)nullptr, T3h);

    // ---- Phase G: conv partials (z=3 over t, N=1536 over j,oc) + shifted sum ----
    g128(T1h, PKh, nullptr, nullptr, nullptr, Cch, 8192, 1536, 512, 8,
         3, (u64)8192 * 512, (u64)1536 * 512, (u64)8192 * 1536, 0, 0);
    hipLaunchKernelGGL(conv_sum, dim3(2048), dim3(256), 0, stream, Cch, outt);

    (void)in_sizes; (void)n_in; (void)out_size; (void)ws_size;
}

// Round 10
// 493.759 us; speedup vs baseline: 2.0226x; 1.0738x over previous
//
#include <hip/hip_runtime.h>
#include <math.h>

typedef unsigned short u16;
typedef unsigned int u32;
typedef unsigned long long u64;

constexpr int kB = 16, kL = 512, kS = 1024, kD = 512, kM = 64;

typedef __attribute__((ext_vector_type(8))) short u16x8;
typedef __attribute__((ext_vector_type(8))) _Float16 f16x8;
typedef __attribute__((ext_vector_type(4))) float f32x4;

__device__ __forceinline__ u16 f2h(float f) {
    _Float16 h = (_Float16)f;
    return *(u16*)&h;
}
__device__ __forceinline__ float h2f(u16 u) {
    _Float16 h = *(_Float16*)&u;
    return (float)h;
}

// ---------------------------------------------------------------------------
// fp16 MFMA GEMM, z-batched: C[z][r,n] = op( sum_k A[z][r,k]*W[z][n,k] + .. )
// 128x128 tile, BK=64. flags: 1=relu, 8=fp16 Ch[r][n], 16=f32 Cout[r][n],
// 32=fp16 transposed Ch[b][n][l], b=r>>lrsh, l=r&((1<<lrsh)-1)
// ---------------------------------------------------------------------------
__global__ __launch_bounds__(256, 4) void gemm_fp16(
    const u16* __restrict__ Abase, const u16* __restrict__ Wbase,
    const float* __restrict__ bias, const float* __restrict__ resid,
    float* __restrict__ Cout, u16* __restrict__ Ch,
    int R, int N, int K, int flags,
    u64 zsA, u64 zsW, u64 zsC, u64 zsR, int lrsh)
{
    __shared__ __attribute__((aligned(16))) u16 Abuf[128 * 64];
    __shared__ __attribute__((aligned(16))) u16 Bbuf[128 * 64];
    const int zz = blockIdx.z;
    Abase += (u64)zz * zsA;
    Wbase += (u64)zz * zsW;
    if (Cout) Cout += (u64)zz * zsC;
    if (Ch)   Ch   += (u64)zz * zsC;
    if (resid) resid += (u64)zz * zsR;

    const int tid = threadIdx.x;
    const int lane = tid & 63;
    const int wave = tid >> 6;
    const int wr = wave >> 1, wc = wave & 1;
    const int ln15 = lane & 15, lq = lane >> 4;
    const int r0 = blockIdx.y * 128, n0 = blockIdx.x * 128;

    f32x4 acc[4][4];
#pragma unroll
    for (int m = 0; m < 4; ++m)
#pragma unroll
        for (int n = 0; n < 4; ++n) acc[m][n] = (f32x4){0.f, 0.f, 0.f, 0.f};

    for (int k0 = 0; k0 < K; k0 += 64) {
        u16x8 av[4], bv[4];
#pragma unroll
        for (int it = 0; it < 4; ++it) {
            int c = it * 256 + tid;
            int row = c >> 3, j = c & 7;
            int jj = j ^ (row & 7);
            av[it] = *(const u16x8*)(Abase + (size_t)(r0 + row) * K + k0 + jj * 8);
            bv[it] = *(const u16x8*)(Wbase + (size_t)(n0 + row) * K + k0 + jj * 8);
        }
        __syncthreads();
#pragma unroll
        for (int it = 0; it < 4; ++it) {
            int c = it * 256 + tid;
            int row = c >> 3, j = c & 7;
            *(u16x8*)&Abuf[row * 64 + j * 8] = av[it];
            *(u16x8*)&Bbuf[row * 64 + j * 8] = bv[it];
        }
        __syncthreads();
#pragma unroll
        for (int h = 0; h < 2; ++h) {
            int kg = lq + h * 4;
            f16x8 af[4], bfv[4];
#pragma unroll
            for (int m = 0; m < 4; ++m) {
                int row = wr * 64 + m * 16 + ln15;
                af[m] = *(const f16x8*)&Abuf[row * 64 + ((kg ^ (row & 7)) << 3)];
            }
#pragma unroll
            for (int n = 0; n < 4; ++n) {
                int col = wc * 64 + n * 16 + ln15;
                bfv[n] = *(const f16x8*)&Bbuf[col * 64 + ((kg ^ (col & 7)) << 3)];
            }
#pragma unroll
            for (int m = 0; m < 4; ++m)
#pragma unroll
                for (int n = 0; n < 4; ++n)
                    acc[m][n] = __builtin_amdgcn_mfma_f32_16x16x32_f16(af[m], bfv[n], acc[m][n], 0, 0, 0);
        }
        __syncthreads();
    }

#pragma unroll
    for (int m = 0; m < 4; ++m) {
#pragma unroll
        for (int n = 0; n < 4; ++n) {
            int gc = n0 + wc * 64 + n * 16 + ln15;
            float bv_ = bias ? bias[gc] : 0.f;
            int gr0 = r0 + wr * 64 + m * 16 + lq * 4;
            float v[4];
#pragma unroll
            for (int rg = 0; rg < 4; ++rg) {
                int gr = gr0 + rg;
                float val = acc[m][n][rg] + bv_;
                if (resid) val += resid[(size_t)gr * N + gc];
                if (flags & 1) val = fmaxf(val, 0.f);
                if (flags & 16) Cout[(size_t)gr * N + gc] = val;
                if (flags & 8)  Ch[(size_t)gr * N + gc] = f2h(val);
                v[rg] = val;
            }
            if (flags & 32) {
                int bb = gr0 >> lrsh;
                int l_ = gr0 & ((1 << lrsh) - 1);
                ushort4 o;
                o.x = f2h(v[0]); o.y = f2h(v[1]); o.z = f2h(v[2]); o.w = f2h(v[3]);
                *(ushort4*)&Ch[(((size_t)bb * N + gc) << lrsh) + l_] = o;
            }
        }
    }
}

// ---------------------------------------------------------------------------
// 64x64-tile fp16 GEMM for thin/batched shapes. Same flags as gemm_fp16.
// ---------------------------------------------------------------------------
__global__ __launch_bounds__(256, 4) void gemm64(
    const u16* __restrict__ Abase, const u16* __restrict__ Wbase,
    const float* __restrict__ bias, const float* __restrict__ resid,
    float* __restrict__ Cout, u16* __restrict__ Ch,
    int R, int N, int K, int flags,
    u64 zsA, u64 zsW, u64 zsC, u64 zsR, int lrsh)
{
    __shared__ __attribute__((aligned(16))) u16 Abuf[64 * 64];
    __shared__ __attribute__((aligned(16))) u16 Bbuf[64 * 64];
    const int zz = blockIdx.z;
    Abase += (u64)zz * zsA;
    Wbase += (u64)zz * zsW;
    if (Cout) Cout += (u64)zz * zsC;
    if (Ch)   Ch   += (u64)zz * zsC;
    if (resid) resid += (u64)zz * zsR;

    const int tid = threadIdx.x;
    const int lane = tid & 63;
    const int w = tid >> 6;
    const int ln15 = lane & 15, lq = lane >> 4;
    const int r0 = blockIdx.y * 64, n0 = blockIdx.x * 64;

    f32x4 acc[4];
#pragma unroll
    for (int m = 0; m < 4; ++m) acc[m] = (f32x4){0.f, 0.f, 0.f, 0.f};

    for (int k0 = 0; k0 < K; k0 += 64) {
        u16x8 av[2], bv[2];
#pragma unroll
        for (int it = 0; it < 2; ++it) {
            int c = it * 256 + tid;
            int row = c >> 3, j = c & 7;
            int jj = j ^ (row & 7);
            av[it] = *(const u16x8*)(Abase + (size_t)(r0 + row) * K + k0 + jj * 8);
            bv[it] = *(const u16x8*)(Wbase + (size_t)(n0 + row) * K + k0 + jj * 8);
        }
        __syncthreads();
#pragma unroll
        for (int it = 0; it < 2; ++it) {
            int c = it * 256 + tid;
            int row = c >> 3, j = c & 7;
            *(u16x8*)&Abuf[row * 64 + j * 8] = av[it];
            *(u16x8*)&Bbuf[row * 64 + j * 8] = bv[it];
        }
        __syncthreads();
#pragma unroll
        for (int h = 0; h < 2; ++h) {
            int kg = lq + h * 4;
            int col = w * 16 + ln15;
            f16x8 bf = *(const f16x8*)&Bbuf[col * 64 + ((kg ^ (col & 7)) << 3)];
#pragma unroll
            for (int m = 0; m < 4; ++m) {
                int row = m * 16 + ln15;
                f16x8 af = *(const f16x8*)&Abuf[row * 64 + ((kg ^ (row & 7)) << 3)];
                acc[m] = __builtin_amdgcn_mfma_f32_16x16x32_f16(af, bf, acc[m], 0, 0, 0);
            }
        }
        __syncthreads();
    }

    const int gc = n0 + w * 16 + ln15;
    const float bv_ = bias ? bias[gc] : 0.f;
#pragma unroll
    for (int m = 0; m < 4; ++m) {
        int gr0 = r0 + m * 16 + lq * 4;
        float v[4];
#pragma unroll
        for (int rg = 0; rg < 4; ++rg) {
            int gr = gr0 + rg;
            float val = acc[m][rg] + bv_;
            if (resid) val += resid[(size_t)gr * N + gc];
            if (flags & 1) val = fmaxf(val, 0.f);
            if (flags & 16) Cout[(size_t)gr * N + gc] = val;
            if (flags & 8)  Ch[(size_t)gr * N + gc] = f2h(val);
            v[rg] = val;
        }
        if (flags & 32) {
            int bb = gr0 >> lrsh;
            int l_ = gr0 & ((1 << lrsh) - 1);
            ushort4 o;
            o.x = f2h(v[0]); o.y = f2h(v[1]); o.z = f2h(v[2]); o.w = f2h(v[3]);
            *(ushort4*)&Ch[(((size_t)bb * N + gc) << lrsh) + l_] = o;
        }
    }
}

// ---------------------------------------------------------------------------
// Fused prep: all weight casts, K|V weight/bias concat, cross cast, twiddles.
// ---------------------------------------------------------------------------
__global__ __launch_bounds__(256) void prep(
    const float* __restrict__ wq, const float* __restrict__ wk,
    const float* __restrict__ wv, const float* __restrict__ wo,
    const float* __restrict__ ff1, const float* __restrict__ ff2,
    const float* __restrict__ dw1, const float* __restrict__ dw2,
    const float* __restrict__ dw3, const float* __restrict__ cross,
    const float* __restrict__ bk, const float* __restrict__ bv,
    u16* __restrict__ wqh, u16* __restrict__ wkvh, u16* __restrict__ woh,
    u16* __restrict__ ff1h, u16* __restrict__ ff2h,
    u16* __restrict__ d1w1h, u16* __restrict__ d2w1h, u16* __restrict__ d3w1h,
    u16* __restrict__ crossh, float* __restrict__ bkv,
    u16* __restrict__ tw512, u16* __restrict__ tw1024, u16* __restrict__ tih)
{
    const int gid = blockIdx.x * 256 + threadIdx.x;
    const int stride = gridDim.x * 256;
    for (int i = gid; i < 262144; i += stride) wqh[i] = f2h(wq[i]);
    for (int i = gid; i < 262144; i += stride) wkvh[i] = f2h(wk[i]);
    for (int i = gid; i < 262144; i += stride) wkvh[262144 + i] = f2h(wv[i]);
    for (int i = gid; i < 262144; i += stride) woh[i] = f2h(wo[i]);
    for (int i = gid; i < 1048576; i += stride) ff1h[i] = f2h(ff1[i]);
    for (int i = gid; i < 1048576; i += stride) ff2h[i] = f2h(ff2[i]);
    for (int i = gid; i < 131072; i += stride) d1w1h[i] = f2h(dw1[i]);
    for (int i = gid; i < 131072; i += stride) d2w1h[i] = f2h(dw2[i]);
    for (int i = gid; i < 131072; i += stride) d3w1h[i] = f2h(dw3[i]);
    const float4* c4 = (const float4*)cross;
    for (int i = gid; i < 2097152; i += stride) {
        float4 v = c4[i];
        ushort4 o;
        o.x = f2h(v.x); o.y = f2h(v.y); o.z = f2h(v.z); o.w = f2h(v.w);
        *(ushort4*)&crossh[i * 4] = o;
    }
    for (int i = gid; i < 1024; i += stride) bkv[i] = (i < 512) ? bk[i] : bv[i - 512];
    for (int i = gid; i < 65536; i += stride) {
        int r = i >> 9, l = i & 511;
        int m = r & 63;
        int ph = (m * l) & 511;
        float ang = 6.283185307179586f * (float)ph / 512.0f;
        float s_, c_;
        sincosf(ang, &s_, &c_);
        tw512[i] = f2h((r < 64) ? c_ : -s_);
    }
    for (int i = gid; i < 131072; i += stride) {
        int r = i >> 10, l = i & 1023;
        int m = r & 63;
        int ph = (m * l) & 1023;
        float ang = 6.283185307179586f * (float)ph / 1024.0f;
        float s_, c_;
        sincosf(ang, &s_, &c_);
        tw1024[i] = f2h((r < 64) ? c_ : -s_);
    }
    for (int i = gid; i < 65536; i += stride) {
        int l = i >> 7, r = i & 127;
        int m = r & 63;
        int ph = (m * l) & 511;
        float ang = 6.283185307179586f * (float)ph / 512.0f;
        float s_, c_;
        sincosf(ang, &s_, &c_);
        float val;
        if (r == 0) val = 1.0f / 512.0f;
        else if (r < 64) val = 2.0f * c_ / 512.0f;
        else if (r == 64) val = 0.0f;
        else val = -2.0f * s_ / 512.0f;
        tih[i] = f2h(val);
    }
}

// ---------------------------------------------------------------------------
// Repack FEB weights: wr/wi [d][e][m] fp32 -> FW/FI [m][e][d] fp16.
// grid (512 e, 8 d-tiles); LDS 64x66 u16 tiles (both global sides coalesced).
// ---------------------------------------------------------------------------
__global__ __launch_bounds__(256) void repack_feb(
    const float* __restrict__ wr, const float* __restrict__ wi,
    u16* __restrict__ FW, u16* __restrict__ FI)
{
    __shared__ u16 t0[64][66], t1[64][66];
    const int e = blockIdx.x;
    const int d0 = blockIdx.y * 64;
    const int tid = threadIdx.x;
#pragma unroll
    for (int rep = 0; rep < 16; ++rep) {
        int idx = tid + rep * 256;
        int dd = idx >> 6, mm = idx & 63;
        size_t g = ((size_t)(d0 + dd) * 512 + e) * 64 + mm;
        t0[dd][mm] = f2h(wr[g]);
        t1[dd][mm] = f2h(wi[g]);
    }
    __syncthreads();
#pragma unroll
    for (int rep = 0; rep < 16; ++rep) {
        int idx = tid + rep * 256;
        int mm = idx >> 6, dd = idx & 63;
        size_t o = ((size_t)mm * 512 + e) * 512 + d0 + dd;
        FW[o] = t0[dd][mm];
        FI[o] = t1[dd][mm];
    }
}

// ---------------------------------------------------------------------------
// FEB via MFMA. Per block: one mode m, one 64-wide e-tile; complex GEMM
// om[b][e] = sum_d qf[b][m][d] * (FW + i*FI)[m][e][d], b=16 rows, K=512.
// QF fp32 [b][128][512] (rows 0..63 real, 64..127 imag). OMT fp16 [b][e][r].
// 4 acc streams: rr=qr*Wr, ii=qi*Wi, ri=qr*Wi, ir=qi*Wr.
// ---------------------------------------------------------------------------
__global__ __launch_bounds__(256, 4) void feb_mfma(
    const float* __restrict__ QF, const u16* __restrict__ FW,
    const u16* __restrict__ FI, u16* __restrict__ OMT)
{
    __shared__ __attribute__((aligned(16))) u16 Aq[16 * 64];
    __shared__ __attribute__((aligned(16))) u16 Ai[16 * 64];
    __shared__ __attribute__((aligned(16))) u16 Br[64 * 64];
    __shared__ __attribute__((aligned(16))) u16 Bi[64 * 64];
    const int e0 = blockIdx.x * 64;
    const int m  = blockIdx.y;
    const int tid = threadIdx.x;
    const int lane = tid & 63;
    const int w = tid >> 6;
    const int ln15 = lane & 15, lq = lane >> 4;

    f32x4 arr = (f32x4){0.f, 0.f, 0.f, 0.f};
    f32x4 aii = arr, ari = arr, air = arr;

    for (int d0 = 0; d0 < 512; d0 += 64) {
        // A: 2 arrays x 16 rows(b) x 8 j = 256 vector loads (fp32 -> fp16)
        u16x8 ahv;
        {
            int ar_ = tid >> 7;
            int row = (tid >> 3) & 15;
            int j = tid & 7;
            int jj = j ^ (row & 7);
            const float* src = QF + ((size_t)row * 128 + (ar_ ? 64 + m : m)) * 512 + d0 + jj * 8;
            float4 v0 = *(const float4*)src;
            float4 v1 = *(const float4*)(src + 4);
            ahv[0] = (short)f2h(v0.x); ahv[1] = (short)f2h(v0.y);
            ahv[2] = (short)f2h(v0.z); ahv[3] = (short)f2h(v0.w);
            ahv[4] = (short)f2h(v1.x); ahv[5] = (short)f2h(v1.y);
            ahv[6] = (short)f2h(v1.z); ahv[7] = (short)f2h(v1.w);
        }
        // B: 2 arrays x 64 rows(e) x 8 j = 1024 -> 4 iters
        u16x8 bvv[4];
#pragma unroll
        for (int it = 0; it < 4; ++it) {
            int c = it * 256 + tid;
            int ar_ = c >> 9;
            int row = (c >> 3) & 63;
            int j = c & 7;
            int jj = j ^ (row & 7);
            const u16* src = (ar_ ? FI : FW) + ((size_t)m * 512 + e0 + row) * 512 + d0 + jj * 8;
            bvv[it] = *(const u16x8*)src;
        }
        __syncthreads();
        {
            int ar_ = tid >> 7;
            int row = (tid >> 3) & 15;
            int j = tid & 7;
            *(u16x8*)&((ar_ ? Ai : Aq)[row * 64 + j * 8]) = ahv;
        }
#pragma unroll
        for (int it = 0; it < 4; ++it) {
            int c = it * 256 + tid;
            int ar_ = c >> 9;
            int row = (c >> 3) & 63;
            int j = c & 7;
            *(u16x8*)&((ar_ ? Bi : Br)[row * 64 + j * 8]) = bvv[it];
        }
        __syncthreads();
#pragma unroll
        for (int h = 0; h < 2; ++h) {
            int kg = lq + h * 4;
            f16x8 aqf = *(const f16x8*)&Aq[ln15 * 64 + ((kg ^ (ln15 & 7)) << 3)];
            f16x8 aif = *(const f16x8*)&Ai[ln15 * 64 + ((kg ^ (ln15 & 7)) << 3)];
            int col = w * 16 + ln15;
            f16x8 brf = *(const f16x8*)&Br[col * 64 + ((kg ^ (col & 7)) << 3)];
            f16x8 bif = *(const f16x8*)&Bi[col * 64 + ((kg ^ (col & 7)) << 3)];
            arr = __builtin_amdgcn_mfma_f32_16x16x32_f16(aqf, brf, arr, 0, 0, 0);
            aii = __builtin_amdgcn_mfma_f32_16x16x32_f16(aif, bif, aii, 0, 0, 0);
            ari = __builtin_amdgcn_mfma_f32_16x16x32_f16(aqf, bif, ari, 0, 0, 0);
            air = __builtin_amdgcn_mfma_f32_16x16x32_f16(aif, brf, air, 0, 0, 0);
        }
        __syncthreads();
    }

    const int e = e0 + w * 16 + ln15;
#pragma unroll
    for (int rg = 0; rg < 4; ++rg) {
        int b = lq * 4 + rg;
        float omr = arr[rg] - aii[rg];
        float omi = ari[rg] + air[rg];
        u16* o = OMT + ((size_t)(b * 512 + e)) * 128;
        o[m] = f2h(omr);
        o[64 + m] = f2h(omi);
    }
}

// ---------------------------------------------------------------------------
// Transpose+cast x[b][l][d] fp32 -> xT[b][d][l] fp16. 64x64 LDS tiles.
// ---------------------------------------------------------------------------
__global__ __launch_bounds__(256) void tr_cast_x(
    const float* __restrict__ x, u16* __restrict__ xt)
{
    __shared__ u16 t[64][72];
    const int b = blockIdx.y;
    const int lt = (blockIdx.x >> 3) * 64, dt = (blockIdx.x & 7) * 64;
    const int tid = threadIdx.x;
#pragma unroll
    for (int rep = 0; rep < 16; ++rep) {
        int idx = tid + rep * 256;
        int row = idx >> 6, col = idx & 63;
        t[row][col] = f2h(x[((size_t)b * kL + lt + row) * kD + dt + col]);
    }
    __syncthreads();
#pragma unroll
    for (int rep = 0; rep < 16; ++rep) {
        int idx = tid + rep * 256;
        int row = idx >> 6, col = idx & 63;
        xt[((size_t)b * kD + dt + row) * kL + lt + col] = t[col][row];
    }
}

// ---------------------------------------------------------------------------
// Spectral cross attention, one block per (b,h). QF fp32 [b][128][512];
// KVF fp32 [b][128][1024]. Output OMT fp16 [b][e][r].
// ---------------------------------------------------------------------------
__global__ __launch_bounds__(256) void spectral_attn(
    const float* __restrict__ QF, const float* __restrict__ KVF,
    u16* __restrict__ OMT)
{
    __shared__ float kr[64][65], ki[64][65], sat[64][65];
    const int b = blockIdx.x >> 3, h = blockIdx.x & 7;
    const int tid = threadIdx.x;
    const int dbase = h * 64;
    const float* KVFb = KVF + (size_t)b * 128 * 1024;

    for (int idx = tid; idx < 4096; idx += 256) {
        int j = idx >> 6, dd = idx & 63;
        kr[j][dd] = KVFb[(size_t)j * 1024 + dbase + dd];
        ki[j][dd] = KVFb[(size_t)(64 + j) * 1024 + dbase + dd];
    }
    __syncthreads();

    const int i_ = tid >> 2, jg = tid & 3;
    float s[16];
#pragma unroll
    for (int jj = 0; jj < 16; ++jj) s[jj] = 0.f;
    const float* qrp = QF + ((size_t)b * 128 + i_) * 512 + dbase;
    const float* qip = qrp + (size_t)64 * 512;
    for (int dd = 0; dd < 64; ++dd) {
        float qr = qrp[dd], qi = qip[dd];
#pragma unroll
        for (int jj = 0; jj < 16; ++jj) {
            int j = jg * 16 + jj;
            s[jj] += qr * kr[j][dd] + qi * ki[j][dd];
        }
    }
    float mx = s[0];
#pragma unroll
    for (int jj = 1; jj < 16; ++jj) mx = fmaxf(mx, s[jj]);
    mx = fmaxf(mx, __shfl_xor(mx, 1));
    mx = fmaxf(mx, __shfl_xor(mx, 2));
    float sum = 0.f;
#pragma unroll
    for (int jj = 0; jj < 16; ++jj) { s[jj] = expf(s[jj] - mx); sum += s[jj]; }
    sum += __shfl_xor(sum, 1);
    sum += __shfl_xor(sum, 2);
    float rinv = 1.0f / sum;
#pragma unroll
    for (int jj = 0; jj < 16; ++jj) sat[i_][jg * 16 + jj] = s[jj] * rinv;
    __syncthreads();

    const int dd = tid & 63, ig = tid >> 6;
    float ar[16], ai[16];
#pragma unroll
    for (int ii = 0; ii < 16; ++ii) { ar[ii] = 0.f; ai[ii] = 0.f; }
    const float* VFb = KVFb + 512 + dbase + dd;
    for (int j = 0; j < 64; ++j) {
        float vr = VFb[(size_t)j * 1024];
        float vi = VFb[(size_t)(64 + j) * 1024];
#pragma unroll
        for (int ii = 0; ii < 16; ++ii) {
            float a = sat[ig * 16 + ii][j];
            ar[ii] += a * vr;
            ai[ii] += a * vi;
        }
    }
    u16* o = OMT + ((size_t)(b * 512 + dbase + dd)) * 128 + ig * 16;
    u16x8 v0, v1, w0, w1;
#pragma unroll
    for (int q = 0; q < 8; ++q) {
        v0[q] = (short)f2h(ar[q]);     v1[q] = (short)f2h(ar[8 + q]);
        w0[q] = (short)f2h(ai[q]);     w1[q] = (short)f2h(ai[8 + q]);
    }
    *(u16x8*)(o) = v0;
    *(u16x8*)(o + 8) = v1;
    *(u16x8*)(o + 64) = w0;
    *(u16x8*)(o + 72) = w1;
}

// ---------------------------------------------------------------------------
// MoE decomposition epilogue.
// ---------------------------------------------------------------------------
__global__ __launch_bounds__(256) void decomp_apply(
    const float* __restrict__ x, const float* __restrict__ logits,
    float* __restrict__ xout, u16* __restrict__ xout_h, u16* __restrict__ tout_h)
{
    int idx = blockIdx.x * 256 + threadIdx.x;
    if (idx >= kB * kL * kD) return;
    int d = idx & 511;
    int l = (idx >> 9) & 511;
    int b = idx >> 18;
    const float* lg = logits + ((size_t)b * kL + l) * 3;
    float g0 = lg[0], g1 = lg[1], g2 = lg[2];
    float m = fmaxf(g0, fmaxf(g1, g2));
    float e0 = expf(g0 - m), e1 = expf(g1 - m), e2 = expf(g2 - m);
    float inv = 1.0f / (e0 + e1 + e2);
    g0 = e0 * inv; g1 = e1 * inv; g2 = e2 * inv;

    const float* xb = x + (size_t)b * kL * kD + d;
    float v[7];
#pragma unroll
    for (int j = 0; j < 7; ++j) {
        int ls = l + j - 3;
        v[j] = (ls >= 0 && ls < kL) ? xb[(size_t)ls * kD] : 0.f;
    }
    float s3 = (v[2] + v[3] + v[4]) * (1.0f / 3.0f);
    float s5 = (v[1] + v[2] + v[3] + v[4] + v[5]) * 0.2f;
    float s7 = (v[0] + v[1] + v[2] + v[3] + v[4] + v[5] + v[6]) * (1.0f / 7.0f);
    float trend = g0 * s3 + g1 * s5 + g2 * s7;
    float res = v[3] - trend;
    if (xout) xout[idx] = res;
    if (xout_h) xout_h[idx] = f2h(res);
    tout_h[idx] = f2h(trend);
}

// ---------------------------------------------------------------------------
// Gate layer 2, K-quarter split: thread (row, q); shuffle-combine over quad.
// grid 128 x 256.
// ---------------------------------------------------------------------------
__global__ __launch_bounds__(256) void gate2(
    const u16* __restrict__ GH, const float* __restrict__ w2,
    const float* __restrict__ b2, float* __restrict__ logits)
{
    __shared__ float w2l[3][256];
    int tid = threadIdx.x;
    for (int i = tid; i < 768; i += 256) w2l[i >> 8][i & 255] = w2[i];
    __syncthreads();
    int gid = blockIdx.x * 256 + tid;
    int r = gid >> 2, q = gid & 3;
    float s0 = 0.f, s1 = 0.f, s2 = 0.f;
    const u16* g = GH + (size_t)r * 256 + q * 64;
    for (int c0 = 0; c0 < 64; c0 += 8) {
        uint4 u = *(const uint4*)&g[c0];
        u32 w[4] = {u.x, u.y, u.z, u.w};
#pragma unroll
        for (int p = 0; p < 4; ++p) {
            float f0 = h2f((u16)(w[p] & 0xFFFF));
            float f1 = h2f((u16)(w[p] >> 16));
            int c = q * 64 + c0 + p * 2;
            s0 += f0 * w2l[0][c] + f1 * w2l[0][c + 1];
            s1 += f0 * w2l[1][c] + f1 * w2l[1][c + 1];
            s2 += f0 * w2l[2][c] + f1 * w2l[2][c + 1];
        }
    }
    s0 += __shfl_xor(s0, 1); s0 += __shfl_xor(s0, 2);
    s1 += __shfl_xor(s1, 1); s1 += __shfl_xor(s1, 2);
    s2 += __shfl_xor(s2, 1); s2 += __shfl_xor(s2, 2);
    if (q == 0) {
        logits[(size_t)r * 3 + 0] = s0 + b2[0];
        logits[(size_t)r * 3 + 1] = s1 + b2[1];
        logits[(size_t)r * 3 + 2] = s2 + b2[2];
    }
}

// Repack conv weights p[o,d,j] (fp32) -> pk[t][j][o][d] (fp16)
__global__ void repack_p(const float* __restrict__ p1, const float* __restrict__ p2,
                         const float* __restrict__ p3, u16* __restrict__ pk)
{
    int idx = blockIdx.x * 256 + threadIdx.x;
    if (idx >= 3 * 3 * 512 * 512) return;
    int d = idx & 511;
    int oc = (idx >> 9) & 511;
    int j = (idx / (512 * 512)) % 3;
    int t = idx / (3 * 512 * 512);
    const float* p = (t == 0) ? p1 : (t == 1) ? p2 : p3;
    pk[idx] = f2h(p[(size_t)oc * 512 * 3 + (size_t)d * 3 + j]);
}

// ---------------------------------------------------------------------------
// Conv epilogue: outt[b][l][oc] = sum_{t,j} Cc[t][b*512+((l+j-1)%512)][j*512+oc]
// ---------------------------------------------------------------------------
__global__ __launch_bounds__(256) void conv_sum(
    const u16* __restrict__ Cc, float* __restrict__ outt)
{
    int gid = blockIdx.x * 256 + threadIdx.x;   // 524288 items
    int ocg = gid & 63;
    int r = gid >> 6;
    int b = r >> 9, l = r & 511;
    float s[8];
#pragma unroll
    for (int q = 0; q < 8; ++q) s[q] = 0.f;
#pragma unroll
    for (int t = 0; t < 3; ++t) {
#pragma unroll
        for (int j = 0; j < 3; ++j) {
            int lr = (l + j + 511) & 511;
            const u16x8 v = *(const u16x8*)&Cc[(size_t)t * 8192 * 1536 +
                ((size_t)(b * 512 + lr)) * 1536 + j * 512 + ocg * 8];
#pragma unroll
            for (int q = 0; q < 8; ++q) s[q] += h2f((u16)v[q]);
        }
    }
    float4 o0 = {s[0], s[1], s[2], s[3]};
    float4 o1 = {s[4], s[5], s[6], s[7]};
    *(float4*)&outt[(size_t)r * 512 + ocg * 8] = o0;
    *(float4*)&outt[(size_t)r * 512 + ocg * 8 + 4] = o1;
}

// ---------------------------------------------------------------------------
extern "C" void kernel_launch(void* const* d_in, const int* in_sizes, int n_in,
                              void* d_out, int out_size, void* d_ws, size_t ws_size,
                              hipStream_t stream)
{
    const float* x_in   = (const float*)d_in[0];
    const float* cross  = (const float*)d_in[1];
    const float* feb_wr = (const float*)d_in[2];
    const float* feb_wi = (const float*)d_in[3];
    const float* wq = (const float*)d_in[4];
    const float* bq = (const float*)d_in[5];
    const float* wk = (const float*)d_in[6];
    const float* bk = (const float*)d_in[7];
    const float* wv = (const float*)d_in[8];
    const float* bv = (const float*)d_in[9];
    const float* wo = (const float*)d_in[10];
    const float* bo = (const float*)d_in[11];
    const float* w_ff1 = (const float*)d_in[12];
    const float* w_ff2 = (const float*)d_in[13];
    const float* d1_w1 = (const float*)d_in[14];
    const float* d1_b1 = (const float*)d_in[15];
    const float* d1_w2 = (const float*)d_in[16];
    const float* d1_b2 = (const float*)d_in[17];
    const float* d2_w1 = (const float*)d_in[18];
    const float* d2_b1 = (const float*)d_in[19];
    const float* d2_w2 = (const float*)d_in[20];
    const float* d2_b2 = (const float*)d_in[21];
    const float* d3_w1 = (const float*)d_in[22];
    const float* d3_b1 = (const float*)d_in[23];
    const float* d3_w2 = (const float*)d_in[24];
    const float* d3_b2 = (const float*)d_in[25];
    const float* p1 = (const float*)d_in[26];
    const float* p2 = (const float*)d_in[27];
    const float* p3 = (const float*)d_in[28];

    // workspace (float offsets); end 42,427,392 floats = 169.7 MB
    float* ws = (float*)d_ws;
    float* X    = ws;                      // 4,194,304
    float* XT   = ws + 4194304;            // 4,194,304
    u16*  KVt   = (u16*)(ws + 8388608);    // [16][1024][1024] u16 = 8,388,608 f
    u16*  Q0t   = (u16*)(ws + 16777216);   // [16][512][512] u16 = 2,097,152 f
    u16*  T1h   = (u16*)(ws + 18874368);   // 2,097,152 f each; T1,T2,T3 contiguous
    u16*  T2h   = (u16*)(ws + 20971520);
    u16*  T3h   = (u16*)(ws + 23068672);
    float* QF   = ws + 25165824;           // [16][128][512] f32 = 1,048,576
    float* KVF  = ws + 26214400;           // [16][128][1024] f32 = 2,097,152
    u16*  OMTh  = (u16*)(ws + 28311552);   // [16][512][128] u16 = 524,288 f
    u16*  crossh = (u16*)(ws + 29884416);  // [16384][512] u16 = 4,194,304 f
    u16*  Xh    = (u16*)(ws + 34078720);   // 2,097,152 f
    u16*  XTh   = (u16*)(ws + 36175872);   // 2,097,152 f
    u16*  GHh   = (u16*)(ws + 38273024);   // 1,048,576 f
    float* GLG  = ws + 39321600;           // 24,576
    u16*  wqh   = (u16*)(ws + 39346176);   // u16 chain below
    u16*  wkvh  = wqh + 262144;            // 524,288 u16 ([wk; wv])
    u16*  woh   = wkvh + 524288;
    u16*  ff1h  = woh + 262144;            // 1,048,576 u16
    u16*  ff2h  = ff1h + 1048576;
    u16*  d1w1h = ff2h + 1048576;          // 131,072 u16 each
    u16*  d2w1h = d1w1h + 131072;
    u16*  d3w1h = d2w1h + 131072;
    u16*  PKh   = d3w1h + 131072;          // 2,359,296 u16 -> ends 42,295,296 f
    u16*  TW512h  = (u16*)(ws + 42295296); // 65,536 u16
    u16*  TW1024h = (u16*)(ws + 42328064); // 131,072 u16
    u16*  TIh     = (u16*)(ws + 42393600); // 65,536 u16
    float* bkv    = ws + 42426368;         // 1,024
    // overlays:
    u16*  FWh   = (u16*)X;                 // phase A FEB weights real [m][e][d] (16,777,216 u16 = X+XT)
    u16*  FIh   = (u16*)KVt;               // phase A FEB weights imag (16,777,216 u16)
    u16*  xTh   = Q0t;                     // phase A xT (Q0t free until phase C)
    u16*  HIDh  = KVt;                     // phase E hidden (16,777,216 u16)
    u16*  Qh    = Q0t;                     // phase C post-attn overlay
    u16*  Cch   = (u16*)ws;                // phase G conv partials (37,748,736 u16)

    float* outx = (float*)d_out;
    float* outt = outx + 4194304;

    auto g128 = [&](const u16* A, const u16* W, const float* bias, const float* resid,
                    float* C, u16* Cb, int R, int N, int K, int flags,
                    int Z, u64 zsA, u64 zsW, u64 zsC, u64 zsR, int lrsh) {
        dim3 g(N / 128, R / 128, Z);
        hipLaunchKernelGGL(gemm_fp16, g, dim3(256), 0, stream,
                           A, W, bias, resid, C, Cb, R, N, K, flags, zsA, zsW, zsC, zsR, lrsh);
    };
    auto g64 = [&](const u16* A, const u16* W, const float* bias, const float* resid,
                   float* C, u16* Cb, int R, int N, int K, int flags,
                   int Z, u64 zsA, u64 zsW, u64 zsC, u64 zsR, int lrsh) {
        dim3 g(N / 64, R / 64, Z);
        hipLaunchKernelGGL(gemm64, g, dim3(256), 0, stream,
                           A, W, bias, resid, C, Cb, R, N, K, flags, zsA, zsW, zsC, zsR, lrsh);
    };

    // ---- Prep: fused casts + conv repack + FEB weight repack ----
    hipLaunchKernelGGL(prep, dim3(2048), dim3(256), 0, stream,
                       wq, wk, wv, wo, w_ff1, w_ff2, d1_w1, d2_w1, d3_w1, cross, bk, bv,
                       wqh, wkvh, woh, ff1h, ff2h, d1w1h, d2w1h, d3w1h, crossh, bkv,
                       TW512h, TW1024h, TIh);
    hipLaunchKernelGGL(repack_p, dim3(9216), dim3(256), 0, stream, p1, p2, p3, PKh);
    hipLaunchKernelGGL(repack_feb, dim3(512, 8), dim3(256), 0, stream,
                       feb_wr, feb_wi, FWh, FIh);

    // ---- Phase A: x = x + fourier_block(x) ----
    hipLaunchKernelGGL(tr_cast_x, dim3(64, 16), dim3(256), 0, stream, x_in, xTh);
    g64(TW512h, xTh, nullptr, nullptr, QF, nullptr, 128, 512, 512, 16,
        16, 0, (u64)512 * 512, (u64)128 * 512, 0, 0);
    hipLaunchKernelGGL(feb_mfma, dim3(8, 64), dim3(256), 0, stream, QF, FWh, FIh, OMTh);
    g64(TIh, OMTh, nullptr, x_in, X, Xh, 512, 512, 128, 16 | 8,
        16, 0, (u64)512 * 128, (u64)512 * 512, (u64)512 * 512, 0);

    // ---- Phase B: decomp1 ----
    g64(Xh, d1w1h, d1_b1, nullptr, nullptr, GHh, 8192, 256, 512, 1 | 8, 1, 0, 0, 0, 0, 0);
    hipLaunchKernelGGL(gate2, dim3(128), dim3(256), 0, stream, GHh, d1_w2, d1_b2, GLG);
    hipLaunchKernelGGL(decomp_apply, dim3(16384), dim3(256), 0, stream, X, GLG, XT, XTh, T1h);

    // ---- Phase C: x = x + fourier_cross(x, cross) ----
    g64(XTh, wqh, bq, nullptr, nullptr, Q0t, 8192, 512, 512, 32, 1, 0, 0, 0, 0, 9);
    g128(crossh, wkvh, bkv, nullptr, nullptr, KVt, 16384, 1024, 512, 32, 1, 0, 0, 0, 0, 10);
    g64(TW512h, Q0t, nullptr, nullptr, QF, nullptr, 128, 512, 512, 16,
        16, 0, (u64)512 * 512, (u64)128 * 512, 0, 0);
    g64(TW1024h, KVt, nullptr, nullptr, KVF, nullptr, 128, 1024, 1024, 16,
        16, 0, (u64)1024 * 1024, (u64)128 * 1024, 0, 0);
    hipLaunchKernelGGL(spectral_attn, dim3(128), dim3(256), 0, stream, QF, KVF, OMTh);
    g64(TIh, OMTh, nullptr, nullptr, nullptr, Qh, 512, 512, 128, 8,
        16, 0, (u64)512 * 128, (u64)512 * 512, 0, 0);
    g64(Qh, woh, bo, XT, X, Xh, 8192, 512, 512, 16 | 8, 1, 0, 0, 0, 0, 0);

    // ---- Phase D: decomp2 ----
    g64(Xh, d2w1h, d2_b1, nullptr, nullptr, GHh, 8192, 256, 512, 1 | 8, 1, 0, 0, 0, 0, 0);
    hipLaunchKernelGGL(gate2, dim3(128), dim3(256), 0, stream, GHh, d2_w2, d2_b2, GLG);
    hipLaunchKernelGGL(decomp_apply, dim3(16384), dim3(256), 0, stream, X, GLG, XT, XTh, T2h);

    // ---- Phase E: FFN ----
    g128(XTh, ff1h, nullptr, nullptr, nullptr, HIDh, 8192, 2048, 512, 1 | 8, 1, 0, 0, 0, 0, 0);
    g64(HIDh, ff2h, nullptr, XT, X, Xh, 8192, 512, 2048, 16 | 8, 1, 0, 0, 0, 0, 0);

    // ---- Phase F: decomp3 -> d_out x ----
    g64(Xh, d3w1h, d3_b1, nullptr, nullptr, GHh, 8192, 256, 512, 1 | 8, 1, 0, 0, 0, 0, 0);
    hipLaunchKernelGGL(gate2, dim3(128), dim3(256), 0, stream, GHh, d3_w2, d3_b2, GLG);
    hipLaunchKernelGGL(decomp_apply, dim3(16384), dim3(256), 0, stream, X, GLG, outx,
                       (u16*)nullptr, T3h);

    // ---- Phase G: conv partials (z=3 over t, N=1536 over j,oc) + shifted sum ----
    g128(T1h, PKh, nullptr, nullptr, nullptr, Cch, 8192, 1536, 512, 8,
         3, (u64)8192 * 512, (u64)1536 * 512, (u64)8192 * 1536, 0, 0);
    hipLaunchKernelGGL(conv_sum, dim3(2048), dim3(256), 0, stream, Cch, outt);

    (void)in_sizes; (void)n_in; (void)out_size; (void)ws_size;
}